// Round 4
// baseline (99.382 us; speedup 1.0000x reference)
//
#include <hip/hip_runtime.h>
#include <hip/hip_bf16.h>

typedef __attribute__((ext_vector_type(8))) short bf16x8;
typedef __attribute__((ext_vector_type(4))) float f32x4;

#define NPIX 4096
#define NC   128
#define RS128 0.08838834764831845f   // 1/sqrt(128)

// ---------------- scan: packed exclusive prefix (bg low16, hole high16) ----------------
__global__ __launch_bounds__(1024) void sffa_scan(
    const float* __restrict__ mask, int* __restrict__ prefBH, int* __restrict__ cnts)
{
    __shared__ int wsum[16];
    const int tid = threadIdx.x, b = blockIdx.x;
    const int lane = tid & 63, w = tid >> 6;
    float4 mv = *(const float4*)(mask + (size_t)b * NPIX + tid * 4);
    int f0 = mv.x < 0.5f ? 0x10000 : 1;
    int f1 = mv.y < 0.5f ? 0x10000 : 1;
    int f2 = mv.z < 0.5f ? 0x10000 : 1;
    int f3 = mv.w < 0.5f ? 0x10000 : 1;
    int tot = f0 + f1 + f2 + f3;
    int sc = tot;
    #pragma unroll
    for (int d = 1; d < 64; d <<= 1) { int t = __shfl_up(sc, d); if (lane >= d) sc += t; }
    if (lane == 63) wsum[w] = sc;
    __syncthreads();
    if (w == 0) {
        int v = (lane < 16) ? wsum[lane] : 0;
        int s = v;
        #pragma unroll
        for (int d = 1; d < 16; d <<= 1) { int t = __shfl_up(s, d); if (lane >= d) s += t; }
        if (lane < 16) wsum[lane] = s - v;
    }
    __syncthreads();
    int base = wsum[w] + sc - tot;
    int e0 = base, e1 = e0 + f0, e2 = e1 + f1, e3 = e2 + f2;
    *(int4*)(prefBH + (size_t)b * NPIX + tid * 4) = make_int4(e0, e1, e2, e3);
    if (tid == 1023) {
        int total = e3 + f3;
        cnts[b * 2]     = total & 0xffff;   // cntK (background patches)
        cnts[b * 2 + 1] = total >> 16;      // cntQ (hole pixels)
    }
}

// ---------------- prep: compacted Knc/Kc/Qc rows + s0 ----------------
__global__ __launch_bounds__(256) void sffa_prep(
    const float* __restrict__ x, const float* __restrict__ mask,
    const int* __restrict__ prefBH,
    ushort* __restrict__ KnW, ushort* __restrict__ QW, ushort* __restrict__ KcW,
    float* __restrict__ s0c)
{
    __shared__ float xs[128][69];
    __shared__ float ms[64];
    __shared__ float rinv[64];
    __shared__ float ssum[64];
    __shared__ float2 part[4][64];
    __shared__ int se[64];
    const int tid = threadIdx.x;
    const int b = blockIdx.x >> 6, nblk = blockIdx.x & 63;
    const int n0 = nblk * 64;
    const float* xb = x + (size_t)b * NC * NPIX;

    #pragma unroll
    for (int it = 0; it < 8; ++it) {
        int e4 = it * 256 + tid;
        int c = e4 >> 4, n4 = (e4 & 15) * 4;
        float4 v = *(const float4*)(xb + (size_t)c * NPIX + n0 + n4);
        xs[c][n4+0] = v.x; xs[c][n4+1] = v.y; xs[c][n4+2] = v.z; xs[c][n4+3] = v.w;
    }
    if (tid < 16) {
        float4 mv = *(const float4*)(mask + (size_t)b * NPIX + n0 + tid * 4);
        ms[tid*4+0] = mv.x; ms[tid*4+1] = mv.y; ms[tid*4+2] = mv.z; ms[tid*4+3] = mv.w;
    }
    if (tid >= 192) {
        int j = tid - 192;
        se[j] = prefBH[(size_t)b * NPIX + n0 + j];
    }
    __syncthreads();
    {
        int p = tid & 63, qd = tid >> 6;
        float m = ms[p];
        float s2 = 0.f, s1 = 0.f;
        #pragma unroll
        for (int i = 0; i < 32; ++i) {
            float xv = xs[qd*32 + i][p];
            float k = fmaf(xv, m, 1e-7f);
            s2 = fmaf(k, k, s2);
            s1 += xv;
        }
        part[qd][p] = make_float2(s2, s1);
    }
    __syncthreads();
    if (tid < 64) {
        float2 t0 = part[0][tid], t1 = part[1][tid], t2 = part[2][tid], t3 = part[3][tid];
        rinv[tid] = rsqrtf(t0.x + t1.x + t2.x + t3.x);
        ssum[tid] = (t0.y + t1.y + t2.y + t3.y) * RS128;
    }
    __syncthreads();
    #pragma unroll
    for (int it = 0; it < 16; ++it) {
        int e2 = it * 256 + tid;
        int n = e2 >> 6, cp = (e2 & 63) * 2;
        int pe = se[n];
        float x0 = xs[cp][n], x1 = xs[cp+1][n];
        if (ms[n] > 0.5f) {
            int slot = pe & 0xffff;
            float k0 = x0 + 1e-7f, k1 = x1 + 1e-7f;
            float r = rinv[n];
            size_t base = ((size_t)b * NPIX + slot) * NC + cp;
            __hip_bfloat162 kn, kv;
            kn.x = __float2bfloat16(k0 * r); kn.y = __float2bfloat16(k1 * r);
            kv.x = __float2bfloat16(k0);     kv.y = __float2bfloat16(k1);
            *(__hip_bfloat162*)(KnW + base) = kn;
            *(__hip_bfloat162*)(KcW + base) = kv;
        } else {
            int slot = pe >> 16;
            __hip_bfloat162 q;
            q.x = __float2bfloat16(x0); q.y = __float2bfloat16(x1);
            *(__hip_bfloat162*)(QW + ((size_t)b * NPIX + slot) * NC + cp) = q;
        }
    }
    if (tid < 64 && ms[tid] < 0.5f)
        s0c[(size_t)b * NPIX + (se[tid] >> 16)] = ssum[tid];
}

// ---------------- vt: transpose compact Kc[slot][c] -> Vtc[c][slot] ----------------
__global__ __launch_bounds__(256) void sffa_vt(
    const ushort* __restrict__ KcW, const int* __restrict__ cnts,
    ushort* __restrict__ VtW)
{
    const int b = blockIdx.x >> 6, t = blockIdx.x & 63;
    if (t * 64 >= cnts[b * 2]) return;
    __shared__ ushort tile[64][128];
    const int tid = threadIdx.x;
    const ushort* src = KcW + ((size_t)b * NPIX + t * 64) * NC;
    #pragma unroll
    for (int it = 0; it < 4; ++it) {
        int idx = it * 256 + tid;
        int r = idx >> 4, cq = (idx & 15) * 8;
        *(int4*)&tile[r][cq] = *(const int4*)(src + (size_t)r * NC + cq);
    }
    __syncthreads();
    const int c = tid >> 1, sh = (tid & 1) * 32;
    ushort* dst = VtW + ((size_t)b * NC + c) * NPIX + t * 64 + sh;
    #pragma unroll
    for (int q8 = 0; q8 < 4; ++q8) {
        ushort tmp[8];
        #pragma unroll
        for (int i = 0; i < 8; ++i) tmp[i] = tile[sh + q8 * 8 + i][c];
        *(int4*)(dst + q8 * 8) = *(const int4*)tmp;
    }
}

// ---------------- flash attention over compacted keys/queries ----------------
#define L_BUF 32768
#define L_P   65536
#define L_ML  75776
#define L_SZ  76800

__global__ __launch_bounds__(512, 4) void sffa_attn(
    const ushort* __restrict__ KnW, const ushort* __restrict__ QW,
    const ushort* __restrict__ VtW, const int* __restrict__ cnts,
    ushort* __restrict__ partW, float* __restrict__ mlW, int KS)
{
    __shared__ __align__(16) char smem[L_SZ];
    const int tid  = threadIdx.x;
    const int w = tid >> 6, lane = tid & 63;
    const int l15 = lane & 15, g = lane >> 4;
    const int nwg = gridDim.x;
    const int bx = ((int)blockIdx.x & 7) * (nwg >> 3) + ((int)blockIdx.x >> 3);
    const int per = 64 * KS;
    const int b = bx / per;
    const int rem = bx - b * per;
    const int qblk = rem / KS, ks = rem - (rem / KS) * KS;
    const int q0 = qblk * 64;
    const int cntK = cnts[b * 2], cntQ = cnts[b * 2 + 1];
    if (q0 >= cntQ) return;
    const int blk = (b * 64 + qblk) * KS + ks;

    const int nk64 = (cntK + 63) >> 6;
    const int tpk  = (nk64 + KS - 1) / KS;
    const int t0   = ks * tpk;
    const int t1   = min(t0 + tpk, nk64);
    const int NTK  = t1 - t0;

    if (NTK <= 0) {
        unsigned* pz = (unsigned*)(partW + (size_t)blk * 8192);
        #pragma unroll
        for (int i = 0; i < 8; ++i) pz[i * 512 + tid] = 0u;
        if (tid < 64)
            *(float2*)(mlW + ((size_t)blk * 64 + tid) * 2) = make_float2(-1e30f, 0.f);
        return;
    }

    const int half = w >> 2;
    const int wq   = w & 3;
    const int kbase = t0 * 64;

    const ushort* Knb = KnW + (size_t)b * NPIX * NC;
    const ushort* Qb  = QW  + (size_t)b * NPIX * NC + (size_t)q0 * NC;
    const ushort* Vtb = VtW + (size_t)b * NC * NPIX;

    // ---- stage Q tile, read q-fragments ----
    #pragma unroll
    for (int it = 0; it < 2; ++it) {
        int L = (it * 512 + tid) * 16;
        int row = L >> 8, col = L & 255;
        int4 v = *(const int4*)((const char*)Qb + L);
        *(int4*)(smem + row * 256 + (col ^ ((row & 15) << 4))) = v;
    }
    __syncthreads();
    bf16x8 qf[4];
    {
        int qrow = wq * 16 + l15;
        #pragma unroll
        for (int kc = 0; kc < 4; ++kc)
            qf[kc] = *(const bf16x8*)(smem + qrow * 256 + ((64*kc + 16*g) ^ (l15 << 4)));
    }
    __syncthreads();

    const int kOff = (tid >> 4) * 256 + (((tid & 15) * 16) ^ (((tid >> 4) & 15) << 4));
    const int cV = tid >> 3, sV = tid & 7;
    const int vOff = cV * 128 + ((sV * 16) ^ ((cV & 7) << 4));
    const int4* kgbase = (const int4*)(Knb + (size_t)kbase * NC);
    const ushort* vgbase = Vtb + (size_t)cV * NPIX + kbase + sV * 8;

    int4 pr0, pr1, pr2, pr3;
    pr0 = kgbase[tid]; pr1 = kgbase[512 + tid];
    pr2 = *(const int4*)(vgbase);
    pr3 = *(const int4*)(vgbase + (size_t)64 * NPIX);
    {
        char* base = smem;
        *(int4*)(base + kOff) = pr0;
        *(int4*)(base + kOff + 8192) = pr1;
        *(int4*)(base + 16384 + vOff) = pr2;
        *(int4*)(base + 16384 + vOff + 8192) = pr3;
    }
    if (NTK > 1) {
        pr0 = kgbase[1024 + tid]; pr1 = kgbase[1536 + tid];
        pr2 = *(const int4*)(vgbase + 64);
        pr3 = *(const int4*)(vgbase + (size_t)64 * NPIX + 64);
    }
    __syncthreads();

    f32x4 acc[8];
    const f32x4 fzero = {0.f, 0.f, 0.f, 0.f};
    #pragma unroll
    for (int i = 0; i < 8; ++i) acc[i] = fzero;
    float mrun = -1e30f, lrun = 0.f;
    char* Pw = smem + L_P + w * 1280;

    for (int kt = 0; kt < NTK; ++kt) {
        if (kt + 1 < NTK) {
            char* base = smem + ((kt + 1) & 1) * L_BUF;
            *(int4*)(base + kOff) = pr0;
            *(int4*)(base + kOff + 8192) = pr1;
            *(int4*)(base + 16384 + vOff) = pr2;
            *(int4*)(base + 16384 + vOff + 8192) = pr3;
        }
        if (kt + 2 < NTK) {
            pr0 = kgbase[(kt + 2) * 1024 + tid];
            pr1 = kgbase[(kt + 2) * 1024 + 512 + tid];
            pr2 = *(const int4*)(vgbase + (kt + 2) * 64);
            pr3 = *(const int4*)(vgbase + (size_t)64 * NPIX + (kt + 2) * 64);
        }
        char* bb = smem + (kt & 1) * L_BUF;
        f32x4 sa0 = fzero, sa1 = fzero;
        {
            const char* rb0 = bb + (half * 32 + l15) * 256;
            const char* rb1 = rb0 + 4096;
            const int sw = l15 << 4;
            __builtin_amdgcn_s_setprio(1);
            #pragma unroll
            for (int kc = 0; kc < 4; ++kc) {
                int off = (64 * kc + 16 * g) ^ sw;
                bf16x8 a0 = *(const bf16x8*)(rb0 + off);
                bf16x8 a1 = *(const bf16x8*)(rb1 + off);
                sa0 = __builtin_amdgcn_mfma_f32_16x16x32_bf16(a0, qf[kc], sa0, 0, 0, 0);
                sa1 = __builtin_amdgcn_mfma_f32_16x16x32_bf16(a1, qf[kc], sa1, 0, 0, 0);
            }
            __builtin_amdgcn_s_setprio(0);
        }
        // mask invalid keys in the last (partial) tile
        {
            int kg0 = (t0 + kt) * 64;
            if (kg0 + 64 > cntK) {
                int kb = cntK - kg0;
                int kr = half * 32 + 4 * g;
                #pragma unroll
                for (int r = 0; r < 4; ++r) {
                    if (kr + r >= kb)      sa0[r] = -3e38f;
                    if (kr + 16 + r >= kb) sa1[r] = -3e38f;
                }
            }
        }
        float tmax = fmaxf(fmaxf(fmaxf(sa0[0], sa0[1]), fmaxf(sa0[2], sa0[3])),
                           fmaxf(fmaxf(sa1[0], sa1[1]), fmaxf(sa1[2], sa1[3])));
        tmax = fmaxf(tmax, __shfl_xor(tmax, 16));
        tmax = fmaxf(tmax, __shfl_xor(tmax, 32));
        bool grow = !__all(tmax <= mrun + 8.f);
        float mnew = grow ? fmaxf(mrun, tmax) : mrun;
        float p0[4], p1[4];
        float ts = 0.f;
        #pragma unroll
        for (int r = 0; r < 4; ++r) { p0[r] = __expf(sa0[r] - mnew); ts += p0[r]; }
        #pragma unroll
        for (int r = 0; r < 4; ++r) { p1[r] = __expf(sa1[r] - mnew); ts += p1[r]; }
        ts += __shfl_xor(ts, 16);
        ts += __shfl_xor(ts, 32);
        if (grow) {
            float sc = __expf(mrun - mnew);
            lrun = lrun * sc + ts;
            float scr[4];
            #pragma unroll
            for (int r = 0; r < 4; ++r) scr[r] = __shfl(sc, 4 * g + r);
            #pragma unroll
            for (int ct = 0; ct < 8; ++ct) {
                acc[ct][0] *= scr[0]; acc[ct][1] *= scr[1];
                acc[ct][2] *= scr[2]; acc[ct][3] *= scr[3];
            }
            mrun = mnew;
        } else {
            lrun += ts;
        }
        union { __hip_bfloat162 h; unsigned u; } ua0, ua1, ub0, ub1;
        ua0.h.x = __float2bfloat16(p0[0]); ua0.h.y = __float2bfloat16(p0[1]);
        ua1.h.x = __float2bfloat16(p0[2]); ua1.h.y = __float2bfloat16(p0[3]);
        ub0.h.x = __float2bfloat16(p1[0]); ub0.h.y = __float2bfloat16(p1[1]);
        ub1.h.x = __float2bfloat16(p1[2]); ub1.h.y = __float2bfloat16(p1[3]);
        *(int2*)(Pw + l15 * 80 +      8 * g) = make_int2((int)ua0.u, (int)ua1.u);
        *(int2*)(Pw + l15 * 80 + 32 + 8 * g) = make_int2((int)ub0.u, (int)ub1.u);
        bf16x8 pf = *(const bf16x8*)(Pw + l15 * 80 + 16 * g);
        {
            const char* vb = bb + 16384;
            __builtin_amdgcn_s_setprio(1);
            #pragma unroll
            for (int ct = 0; ct < 8; ++ct) {
                int c = 16 * ct + l15;
                bf16x8 vf = *(const bf16x8*)(vb + c * 128 +
                                             ((64 * half + 16 * g) ^ ((c & 7) << 4)));
                acc[ct] = __builtin_amdgcn_mfma_f32_16x16x32_bf16(pf, vf, acc[ct], 0, 0, 0);
            }
            __builtin_amdgcn_s_setprio(0);
        }
        __syncthreads();
    }

    // ---- merge key-half partials; write unnormalized partial + (m,l) ----
    float* ma = (float*)(smem + L_ML);
    float* la = ma + 64; float* mb = la + 64; float* lb = mb + 64;
    const int q = wq * 16 + l15;
    if (g == 0) {
        if (half == 0) { ma[q] = mrun; la[q] = lrun; }
        else           { mb[q] = mrun; lb[q] = lrun; }
    }
    __syncthreads();
    float* agg = (float*)smem;
    {
        float mstar = fmaxf(ma[q], mb[q]);
        float f = __expf(mrun - mstar);
        float fr[4];
        #pragma unroll
        for (int r = 0; r < 4; ++r) fr[r] = __shfl(f, 4 * g + r);
        if (half == 1) {
            #pragma unroll
            for (int ct = 0; ct < 8; ++ct) {
                int c = 16 * ct + l15;
                #pragma unroll
                for (int r = 0; r < 4; ++r)
                    agg[c * 68 + wq * 16 + 4 * g + r] = acc[ct][r] * fr[r];
            }
        }
        __syncthreads();
        if (half == 0) {
            #pragma unroll
            for (int ct = 0; ct < 8; ++ct) {
                int c = 16 * ct + l15;
                #pragma unroll
                for (int r = 0; r < 4; ++r) {
                    int idx = c * 68 + wq * 16 + 4 * g + r;
                    agg[idx] = acc[ct][r] * fr[r] + agg[idx];
                }
            }
        }
    }
    __syncthreads();
    if (tid < 64) {
        float M = fmaxf(ma[tid], mb[tid]);
        float ls = la[tid] * __expf(ma[tid] - M) + lb[tid] * __expf(mb[tid] - M);
        *(float2*)(mlW + ((size_t)blk * 64 + tid) * 2) = make_float2(M, ls);
    }
    ushort* pdst = partW + (size_t)blk * 8192;
    #pragma unroll
    for (int it = 0; it < 8; ++it) {
        int idx = it * 512 + tid;
        int c = idx >> 5, n2 = (idx & 31) * 2;
        __hip_bfloat162 h;
        h.x = __float2bfloat16(agg[c * 68 + n2]);
        h.y = __float2bfloat16(agg[c * 68 + n2 + 1]);
        *(__hip_bfloat162*)(pdst + c * 64 + n2) = h;
    }
}

// ---------------- merge: slot-major coalesced combine -> LDS -> pixel scatter ----------------
__global__ __launch_bounds__(256) void sffa_merge(
    const ushort* __restrict__ partW, const float* __restrict__ mlW,
    const int* __restrict__ prefBH, const float* __restrict__ s0c,
    const int* __restrict__ cnts,
    const float* __restrict__ x, const float* __restrict__ mask,
    float* __restrict__ out, int KS)
{
    __shared__ float aggL[128][68];
    __shared__ float wgt[4][64];
    __shared__ int   boffs[64];
    __shared__ short hid[64];
    const int tid = threadIdx.x;
    const int b = blockIdx.x >> 6, pt = blockIdx.x & 63, n0 = pt * 64;
    const int cntK = cnts[b * 2], cntQ = cnts[b * 2 + 1];
    const float m0f = (float)(NPIX - cntK);
    const float* mkb = mask + (size_t)b * NPIX;
    const int h0 = prefBH[(size_t)b * NPIX + n0] >> 16;
    const int hEnd = (pt < 63) ? (prefBH[(size_t)b * NPIX + n0 + 64] >> 16) : cntQ;

    if (tid < 64) {
        // per-pixel hole index within this tile
        int n = n0 + tid;
        float mv = mkb[n];
        int ph = prefBH[(size_t)b * NPIX + n] >> 16;
        hid[tid] = (mv < 0.5f) ? (short)(ph - h0) : (short)-1;
        // per-slot weights (slots owned by this tile are contiguous [h0, hEnd))
        int slot = h0 + tid;
        int bo = -1;
        if (slot < hEnd) {
            int qb = slot >> 6, so = slot & 63;
            int blkbase = (b * 64 + qb) * KS;
            float s0 = s0c[(size_t)b * NPIX + slot];
            float M = s0;
            float2 mls[4];
            #pragma unroll
            for (int k = 0; k < 4; ++k) {
                if (k < KS) {
                    mls[k] = *(const float2*)(mlW + ((size_t)(blkbase + k) * 64 + so) * 2);
                    M = fmaxf(M, mls[k].x);
                }
            }
            float L = m0f * __expf(s0 - M);
            #pragma unroll
            for (int k = 0; k < 4; ++k)
                if (k < KS) L += mls[k].y * __expf(mls[k].x - M);
            float Linv = 1.f / L;
            #pragma unroll
            for (int k = 0; k < 4; ++k)
                if (k < KS) wgt[k][tid] = __expf(mls[k].x - M) * Linv;
            bo = blkbase * 8192 + so;
        }
        boffs[tid] = bo;
    }
    __syncthreads();

    // coalesced combine: lanes sweep slots (stride-1 ushort), c fixed per wave-iter
    #pragma unroll
    for (int it = 0; it < 32; ++it) {
        int idx = it * 256 + tid;
        int c = idx >> 6, s = idx & 63;
        int bo = boffs[s];
        float v = 0.f;
        if (bo >= 0) {
            #pragma unroll
            for (int k = 0; k < 4; ++k) {
                if (k < KS) {
                    unsigned u = partW[(size_t)bo + (size_t)k * 8192 + c * 64];
                    v += __uint_as_float(u << 16) * wgt[k][s];
                }
            }
        }
        aggL[c][s] = v;
    }
    __syncthreads();

    // per-pixel epilogue: gather from LDS, coalesced float4 store
    const float* xb = x   + (size_t)b * NC * NPIX;
    float* ob       = out + (size_t)b * NC * NPIX;
    #pragma unroll
    for (int it = 0; it < 8; ++it) {
        int idx = it * 256 + tid;
        int c = idx >> 4, j0 = (idx & 15) * 4;
        float4 xi = *(const float4*)(xb + (size_t)c * NPIX + n0 + j0);
        float4 mk = *(const float4*)(mkb + n0 + j0);
        float xv[4] = {xi.x, xi.y, xi.z, xi.w};
        float mv[4] = {mk.x, mk.y, mk.z, mk.w};
        float o[4];
        #pragma unroll
        for (int i = 0; i < 4; ++i) {
            if (mv[i] > 0.5f) o[i] = xv[i];
            else              o[i] = aggL[c][hid[j0 + i]];
        }
        float4 ov = {o[0], o[1], o[2], o[3]};
        *(float4*)(ob + (size_t)c * NPIX + n0 + j0) = ov;
    }
}

extern "C" void kernel_launch(void* const* d_in, const int* in_sizes, int n_in,
                              void* d_out, int out_size, void* d_ws, size_t ws_size,
                              hipStream_t stream) {
    const float* x    = (const float*)d_in[0];
    const float* mask = (const float*)d_in[1];
    char* ws = (char*)d_ws;
    const size_t MBy = 1024 * 1024;

    ushort* KnW = (ushort*)(ws);                      // 4 MB compact Kn
    ushort* QW  = (ushort*)(ws + 4 * MBy);            // 4 MB compact Q
    ushort* VtW = (ushort*)(ws + 8 * MBy);            // 4 MB compact V^T
    ushort* KcW = (ushort*)(ws + 12 * MBy);           // 4 MB compact K (aliases parts)

    size_t need4 = 12 * MBy + 4 * 4 * MBy + 1 * MBy;
    int KS = (ws_size >= need4) ? 4 : 2;
    ushort* partW = (ushort*)(ws + 12 * MBy);                       // KS*4 MB
    char* tail = ws + 12 * MBy + (size_t)KS * 4 * MBy;
    float* mlW    = (float*)(tail);
    int*   prefBH = (int*)(tail + 512 * 1024);
    float* s0c    = (float*)(tail + 512 * 1024 + 64 * 1024);
    int*   cnts   = (int*)(tail + 512 * 1024 + 128 * 1024);

    sffa_scan <<<4,   1024, 0, stream>>>(mask, prefBH, cnts);
    sffa_prep <<<256, 256,  0, stream>>>(x, mask, prefBH, KnW, QW, KcW, s0c);
    sffa_vt   <<<256, 256,  0, stream>>>(KcW, cnts, VtW);
    sffa_attn <<<4 * 64 * KS, 512, 0, stream>>>(KnW, QW, VtW, cnts, partW, mlW, KS);
    sffa_merge<<<256, 256,  0, stream>>>(partW, mlW, prefBH, s0c, cnts, x, mask,
                                         (float*)d_out, KS);
}

// Round 5
// 72.010 us; speedup vs baseline: 1.3801x; 1.3801x over previous
//
#include <hip/hip_runtime.h>
#include <hip/hip_bf16.h>

typedef __attribute__((ext_vector_type(8))) short bf16x8;
typedef __attribute__((ext_vector_type(4))) float f32x4;

#define NPIX 4096
#define NC   128
#define RS128 0.08838834764831845f   // 1/sqrt(128)

// ---------------- scan: packed exclusive prefix (bg low16, hole high16) ----------------
__global__ __launch_bounds__(1024) void sffa_scan(
    const float* __restrict__ mask, int* __restrict__ prefBH, int* __restrict__ cnts)
{
    __shared__ int wsum[16];
    const int tid = threadIdx.x, b = blockIdx.x;
    const int lane = tid & 63, w = tid >> 6;
    float4 mv = *(const float4*)(mask + (size_t)b * NPIX + tid * 4);
    int f0 = mv.x < 0.5f ? 0x10000 : 1;
    int f1 = mv.y < 0.5f ? 0x10000 : 1;
    int f2 = mv.z < 0.5f ? 0x10000 : 1;
    int f3 = mv.w < 0.5f ? 0x10000 : 1;
    int tot = f0 + f1 + f2 + f3;
    int sc = tot;
    #pragma unroll
    for (int d = 1; d < 64; d <<= 1) { int t = __shfl_up(sc, d); if (lane >= d) sc += t; }
    if (lane == 63) wsum[w] = sc;
    __syncthreads();
    if (w == 0) {
        int v = (lane < 16) ? wsum[lane] : 0;
        int s = v;
        #pragma unroll
        for (int d = 1; d < 16; d <<= 1) { int t = __shfl_up(s, d); if (lane >= d) s += t; }
        if (lane < 16) wsum[lane] = s - v;
    }
    __syncthreads();
    int base = wsum[w] + sc - tot;
    int e0 = base, e1 = e0 + f0, e2 = e1 + f1, e3 = e2 + f2;
    *(int4*)(prefBH + (size_t)b * NPIX + tid * 4) = make_int4(e0, e1, e2, e3);
    if (tid == 1023) {
        int total = e3 + f3;
        cnts[b * 2]     = total & 0xffff;   // cntK (background patches)
        cnts[b * 2 + 1] = total >> 16;      // cntQ (hole pixels)
    }
}

// ---------------- prep: compacted Knc/Kc/Qc rows + s0 + slot->pixel map ----------------
__global__ __launch_bounds__(256) void sffa_prep(
    const float* __restrict__ x, const float* __restrict__ mask,
    const int* __restrict__ prefBH,
    ushort* __restrict__ KnW, ushort* __restrict__ QW, ushort* __restrict__ KcW,
    float* __restrict__ s0c, int* __restrict__ pixQ)
{
    __shared__ float xs[128][69];
    __shared__ float ms[64];
    __shared__ float rinv[64];
    __shared__ float ssum[64];
    __shared__ float2 part[4][64];
    __shared__ int se[64];
    const int tid = threadIdx.x;
    const int b = blockIdx.x >> 6, nblk = blockIdx.x & 63;
    const int n0 = nblk * 64;
    const float* xb = x + (size_t)b * NC * NPIX;

    #pragma unroll
    for (int it = 0; it < 8; ++it) {
        int e4 = it * 256 + tid;
        int c = e4 >> 4, n4 = (e4 & 15) * 4;
        float4 v = *(const float4*)(xb + (size_t)c * NPIX + n0 + n4);
        xs[c][n4+0] = v.x; xs[c][n4+1] = v.y; xs[c][n4+2] = v.z; xs[c][n4+3] = v.w;
    }
    if (tid < 16) {
        float4 mv = *(const float4*)(mask + (size_t)b * NPIX + n0 + tid * 4);
        ms[tid*4+0] = mv.x; ms[tid*4+1] = mv.y; ms[tid*4+2] = mv.z; ms[tid*4+3] = mv.w;
    }
    if (tid >= 192) {
        int j = tid - 192;
        se[j] = prefBH[(size_t)b * NPIX + n0 + j];
    }
    __syncthreads();
    {
        int p = tid & 63, qd = tid >> 6;
        float m = ms[p];
        float s2 = 0.f, s1 = 0.f;
        #pragma unroll
        for (int i = 0; i < 32; ++i) {
            float xv = xs[qd*32 + i][p];
            float k = fmaf(xv, m, 1e-7f);
            s2 = fmaf(k, k, s2);
            s1 += xv;
        }
        part[qd][p] = make_float2(s2, s1);
    }
    __syncthreads();
    if (tid < 64) {
        float2 t0 = part[0][tid], t1 = part[1][tid], t2 = part[2][tid], t3 = part[3][tid];
        rinv[tid] = rsqrtf(t0.x + t1.x + t2.x + t3.x);
        ssum[tid] = (t0.y + t1.y + t2.y + t3.y) * RS128;
    }
    __syncthreads();
    #pragma unroll
    for (int it = 0; it < 16; ++it) {
        int e2 = it * 256 + tid;
        int n = e2 >> 6, cp = (e2 & 63) * 2;
        int pe = se[n];
        float x0 = xs[cp][n], x1 = xs[cp+1][n];
        if (ms[n] > 0.5f) {
            int slot = pe & 0xffff;
            float k0 = x0 + 1e-7f, k1 = x1 + 1e-7f;
            float r = rinv[n];
            size_t base = ((size_t)b * NPIX + slot) * NC + cp;
            __hip_bfloat162 kn, kv;
            kn.x = __float2bfloat16(k0 * r); kn.y = __float2bfloat16(k1 * r);
            kv.x = __float2bfloat16(k0);     kv.y = __float2bfloat16(k1);
            *(__hip_bfloat162*)(KnW + base) = kn;
            *(__hip_bfloat162*)(KcW + base) = kv;
        } else {
            int slot = pe >> 16;
            __hip_bfloat162 q;
            q.x = __float2bfloat16(x0); q.y = __float2bfloat16(x1);
            *(__hip_bfloat162*)(QW + ((size_t)b * NPIX + slot) * NC + cp) = q;
        }
    }
    if (tid < 64 && ms[tid] < 0.5f) {
        int slot = se[tid] >> 16;
        s0c [(size_t)b * NPIX + slot] = ssum[tid];
        pixQ[(size_t)b * NPIX + slot] = n0 + tid;
    }
}

// ---------------- vt: transpose compact Kc[slot][c] -> Vtc[c][slot] ----------------
__global__ __launch_bounds__(256) void sffa_vt(
    const ushort* __restrict__ KcW, const int* __restrict__ cnts,
    ushort* __restrict__ VtW)
{
    const int b = blockIdx.x >> 6, t = blockIdx.x & 63;
    if (t * 64 >= cnts[b * 2]) return;
    __shared__ ushort tile[64][128];
    const int tid = threadIdx.x;
    const ushort* src = KcW + ((size_t)b * NPIX + t * 64) * NC;
    #pragma unroll
    for (int it = 0; it < 4; ++it) {
        int idx = it * 256 + tid;
        int r = idx >> 4, cq = (idx & 15) * 8;
        *(int4*)&tile[r][cq] = *(const int4*)(src + (size_t)r * NC + cq);
    }
    __syncthreads();
    const int c = tid >> 1, sh = (tid & 1) * 32;
    ushort* dst = VtW + ((size_t)b * NC + c) * NPIX + t * 64 + sh;
    #pragma unroll
    for (int q8 = 0; q8 < 4; ++q8) {
        ushort tmp[8];
        #pragma unroll
        for (int i = 0; i < 8; ++i) tmp[i] = tile[sh + q8 * 8 + i][c];
        *(int4*)(dst + q8 * 8) = *(const int4*)tmp;
    }
}

// ---------------- flash attention over compacted keys/queries ----------------
#define L_BUF 32768
#define L_P   65536
#define L_ML  75776
#define L_SZ  76800

__global__ __launch_bounds__(512, 4) void sffa_attn(
    const ushort* __restrict__ KnW, const ushort* __restrict__ QW,
    const ushort* __restrict__ VtW, const int* __restrict__ cnts,
    ushort* __restrict__ partW, float* __restrict__ mlW, int KS)
{
    __shared__ __align__(16) char smem[L_SZ];
    const int tid  = threadIdx.x;
    const int w = tid >> 6, lane = tid & 63;
    const int l15 = lane & 15, g = lane >> 4;
    const int nwg = gridDim.x;
    const int bx = ((int)blockIdx.x & 7) * (nwg >> 3) + ((int)blockIdx.x >> 3);
    const int per = 64 * KS;
    const int b = bx / per;
    const int rem = bx - b * per;
    const int qblk = rem / KS, ks = rem - (rem / KS) * KS;
    const int q0 = qblk * 64;
    const int cntK = cnts[b * 2], cntQ = cnts[b * 2 + 1];
    if (q0 >= cntQ) return;
    const int blk = (b * 64 + qblk) * KS + ks;

    const int nk64 = (cntK + 63) >> 6;
    const int tpk  = (nk64 + KS - 1) / KS;
    const int t0   = ks * tpk;
    const int t1   = min(t0 + tpk, nk64);
    const int NTK  = t1 - t0;

    if (NTK <= 0) {
        unsigned* pz = (unsigned*)(partW + (size_t)blk * 8192);
        #pragma unroll
        for (int i = 0; i < 8; ++i) pz[i * 512 + tid] = 0u;
        if (tid < 64)
            *(float2*)(mlW + ((size_t)blk * 64 + tid) * 2) = make_float2(-1e30f, 0.f);
        return;
    }

    const int half = w >> 2;
    const int wq   = w & 3;
    const int kbase = t0 * 64;

    const ushort* Knb = KnW + (size_t)b * NPIX * NC;
    const ushort* Qb  = QW  + (size_t)b * NPIX * NC + (size_t)q0 * NC;
    const ushort* Vtb = VtW + (size_t)b * NC * NPIX;

    // ---- stage Q tile, read q-fragments ----
    #pragma unroll
    for (int it = 0; it < 2; ++it) {
        int L = (it * 512 + tid) * 16;
        int row = L >> 8, col = L & 255;
        int4 v = *(const int4*)((const char*)Qb + L);
        *(int4*)(smem + row * 256 + (col ^ ((row & 15) << 4))) = v;
    }
    __syncthreads();
    bf16x8 qf[4];
    {
        int qrow = wq * 16 + l15;
        #pragma unroll
        for (int kc = 0; kc < 4; ++kc)
            qf[kc] = *(const bf16x8*)(smem + qrow * 256 + ((64*kc + 16*g) ^ (l15 << 4)));
    }
    __syncthreads();

    const int kOff = (tid >> 4) * 256 + (((tid & 15) * 16) ^ (((tid >> 4) & 15) << 4));
    const int cV = tid >> 3, sV = tid & 7;
    const int vOff = cV * 128 + ((sV * 16) ^ ((cV & 7) << 4));
    const int4* kgbase = (const int4*)(Knb + (size_t)kbase * NC);
    const ushort* vgbase = Vtb + (size_t)cV * NPIX + kbase + sV * 8;

    int4 pr0, pr1, pr2, pr3;
    pr0 = kgbase[tid]; pr1 = kgbase[512 + tid];
    pr2 = *(const int4*)(vgbase);
    pr3 = *(const int4*)(vgbase + (size_t)64 * NPIX);
    {
        char* base = smem;
        *(int4*)(base + kOff) = pr0;
        *(int4*)(base + kOff + 8192) = pr1;
        *(int4*)(base + 16384 + vOff) = pr2;
        *(int4*)(base + 16384 + vOff + 8192) = pr3;
    }
    if (NTK > 1) {
        pr0 = kgbase[1024 + tid]; pr1 = kgbase[1536 + tid];
        pr2 = *(const int4*)(vgbase + 64);
        pr3 = *(const int4*)(vgbase + (size_t)64 * NPIX + 64);
    }
    __syncthreads();

    f32x4 acc[8];
    const f32x4 fzero = {0.f, 0.f, 0.f, 0.f};
    #pragma unroll
    for (int i = 0; i < 8; ++i) acc[i] = fzero;
    float mrun = -1e30f, lrun = 0.f;
    char* Pw = smem + L_P + w * 1280;

    for (int kt = 0; kt < NTK; ++kt) {
        if (kt + 1 < NTK) {
            char* base = smem + ((kt + 1) & 1) * L_BUF;
            *(int4*)(base + kOff) = pr0;
            *(int4*)(base + kOff + 8192) = pr1;
            *(int4*)(base + 16384 + vOff) = pr2;
            *(int4*)(base + 16384 + vOff + 8192) = pr3;
        }
        if (kt + 2 < NTK) {
            pr0 = kgbase[(kt + 2) * 1024 + tid];
            pr1 = kgbase[(kt + 2) * 1024 + 512 + tid];
            pr2 = *(const int4*)(vgbase + (kt + 2) * 64);
            pr3 = *(const int4*)(vgbase + (size_t)64 * NPIX + (kt + 2) * 64);
        }
        char* bb = smem + (kt & 1) * L_BUF;
        f32x4 sa0 = fzero, sa1 = fzero;
        {
            const char* rb0 = bb + (half * 32 + l15) * 256;
            const char* rb1 = rb0 + 4096;
            const int sw = l15 << 4;
            __builtin_amdgcn_s_setprio(1);
            #pragma unroll
            for (int kc = 0; kc < 4; ++kc) {
                int off = (64 * kc + 16 * g) ^ sw;
                bf16x8 a0 = *(const bf16x8*)(rb0 + off);
                bf16x8 a1 = *(const bf16x8*)(rb1 + off);
                sa0 = __builtin_amdgcn_mfma_f32_16x16x32_bf16(a0, qf[kc], sa0, 0, 0, 0);
                sa1 = __builtin_amdgcn_mfma_f32_16x16x32_bf16(a1, qf[kc], sa1, 0, 0, 0);
            }
            __builtin_amdgcn_s_setprio(0);
        }
        {
            int kg0 = (t0 + kt) * 64;
            if (kg0 + 64 > cntK) {
                int kb = cntK - kg0;
                int kr = half * 32 + 4 * g;
                #pragma unroll
                for (int r = 0; r < 4; ++r) {
                    if (kr + r >= kb)      sa0[r] = -3e38f;
                    if (kr + 16 + r >= kb) sa1[r] = -3e38f;
                }
            }
        }
        float tmax = fmaxf(fmaxf(fmaxf(sa0[0], sa0[1]), fmaxf(sa0[2], sa0[3])),
                           fmaxf(fmaxf(sa1[0], sa1[1]), fmaxf(sa1[2], sa1[3])));
        tmax = fmaxf(tmax, __shfl_xor(tmax, 16));
        tmax = fmaxf(tmax, __shfl_xor(tmax, 32));
        bool grow = !__all(tmax <= mrun + 8.f);
        float mnew = grow ? fmaxf(mrun, tmax) : mrun;
        float p0[4], p1[4];
        float ts = 0.f;
        #pragma unroll
        for (int r = 0; r < 4; ++r) { p0[r] = __expf(sa0[r] - mnew); ts += p0[r]; }
        #pragma unroll
        for (int r = 0; r < 4; ++r) { p1[r] = __expf(sa1[r] - mnew); ts += p1[r]; }
        ts += __shfl_xor(ts, 16);
        ts += __shfl_xor(ts, 32);
        if (grow) {
            float sc = __expf(mrun - mnew);
            lrun = lrun * sc + ts;
            float scr[4];
            #pragma unroll
            for (int r = 0; r < 4; ++r) scr[r] = __shfl(sc, 4 * g + r);
            #pragma unroll
            for (int ct = 0; ct < 8; ++ct) {
                acc[ct][0] *= scr[0]; acc[ct][1] *= scr[1];
                acc[ct][2] *= scr[2]; acc[ct][3] *= scr[3];
            }
            mrun = mnew;
        } else {
            lrun += ts;
        }
        union { __hip_bfloat162 h; unsigned u; } ua0, ua1, ub0, ub1;
        ua0.h.x = __float2bfloat16(p0[0]); ua0.h.y = __float2bfloat16(p0[1]);
        ua1.h.x = __float2bfloat16(p0[2]); ua1.h.y = __float2bfloat16(p0[3]);
        ub0.h.x = __float2bfloat16(p1[0]); ub0.h.y = __float2bfloat16(p1[1]);
        ub1.h.x = __float2bfloat16(p1[2]); ub1.h.y = __float2bfloat16(p1[3]);
        *(int2*)(Pw + l15 * 80 +      8 * g) = make_int2((int)ua0.u, (int)ua1.u);
        *(int2*)(Pw + l15 * 80 + 32 + 8 * g) = make_int2((int)ub0.u, (int)ub1.u);
        bf16x8 pf = *(const bf16x8*)(Pw + l15 * 80 + 16 * g);
        {
            const char* vb = bb + 16384;
            __builtin_amdgcn_s_setprio(1);
            #pragma unroll
            for (int ct = 0; ct < 8; ++ct) {
                int c = 16 * ct + l15;
                bf16x8 vf = *(const bf16x8*)(vb + c * 128 +
                                             ((64 * half + 16 * g) ^ ((c & 7) << 4)));
                acc[ct] = __builtin_amdgcn_mfma_f32_16x16x32_bf16(pf, vf, acc[ct], 0, 0, 0);
            }
            __builtin_amdgcn_s_setprio(0);
        }
        __syncthreads();
    }

    float* ma = (float*)(smem + L_ML);
    float* la = ma + 64; float* mb = la + 64; float* lb = mb + 64;
    const int q = wq * 16 + l15;
    if (g == 0) {
        if (half == 0) { ma[q] = mrun; la[q] = lrun; }
        else           { mb[q] = mrun; lb[q] = lrun; }
    }
    __syncthreads();
    float* agg = (float*)smem;
    {
        float mstar = fmaxf(ma[q], mb[q]);
        float f = __expf(mrun - mstar);
        float fr[4];
        #pragma unroll
        for (int r = 0; r < 4; ++r) fr[r] = __shfl(f, 4 * g + r);
        if (half == 1) {
            #pragma unroll
            for (int ct = 0; ct < 8; ++ct) {
                int c = 16 * ct + l15;
                #pragma unroll
                for (int r = 0; r < 4; ++r)
                    agg[c * 68 + wq * 16 + 4 * g + r] = acc[ct][r] * fr[r];
            }
        }
        __syncthreads();
        if (half == 0) {
            #pragma unroll
            for (int ct = 0; ct < 8; ++ct) {
                int c = 16 * ct + l15;
                #pragma unroll
                for (int r = 0; r < 4; ++r) {
                    int idx = c * 68 + wq * 16 + 4 * g + r;
                    agg[idx] = acc[ct][r] * fr[r] + agg[idx];
                }
            }
        }
    }
    __syncthreads();
    if (tid < 64) {
        float M = fmaxf(ma[tid], mb[tid]);
        float ls = la[tid] * __expf(ma[tid] - M) + lb[tid] * __expf(mb[tid] - M);
        *(float2*)(mlW + ((size_t)blk * 64 + tid) * 2) = make_float2(M, ls);
    }
    ushort* pdst = partW + (size_t)blk * 8192;
    #pragma unroll
    for (int it = 0; it < 8; ++it) {
        int idx = it * 512 + tid;
        int c = idx >> 5, n2 = (idx & 31) * 2;
        __hip_bfloat162 h;
        h.x = __float2bfloat16(agg[c * 68 + n2]);
        h.y = __float2bfloat16(agg[c * 68 + n2 + 1]);
        *(__hip_bfloat162*)(pdst + c * 64 + n2) = h;
    }
}

// ---------------- copy: out = x (background/default value everywhere) ----------------
__global__ __launch_bounds__(256) void sffa_copy(
    const float4* __restrict__ x, float4* __restrict__ out)
{
    const int i0 = blockIdx.x * 1024 + threadIdx.x;
    #pragma unroll
    for (int j = 0; j < 4; ++j) out[i0 + j * 256] = x[i0 + j * 256];
}

// ---------------- comb: slot-space vectorized combine + scatter to hole pixels ----------------
__global__ __launch_bounds__(256) void sffa_comb(
    const ushort* __restrict__ partW, const float* __restrict__ mlW,
    const float* __restrict__ s0c, const int* __restrict__ pixQ,
    const int* __restrict__ cnts, float* __restrict__ out, int KS)
{
    __shared__ float wgtL[4][64];
    __shared__ int pixnL[64];
    const int tid = threadIdx.x;
    const int bx = blockIdx.x;
    const int b = bx >> 7, qb = (bx >> 1) & 63, ch = bx & 1;
    const int cntK = cnts[b * 2], cntQ = cnts[b * 2 + 1];
    if (qb * 64 >= cntQ) return;
    const int blkbase = (b * 64 + qb) * KS;
    const float m0f = (float)(NPIX - cntK);

    if (tid < 64) {
        int slot = qb * 64 + tid;
        int pix = -1;
        if (slot < cntQ) {
            pix = pixQ[(size_t)b * NPIX + slot];
            float s0 = s0c[(size_t)b * NPIX + slot];
            float M = s0;
            float2 mls[4];
            #pragma unroll
            for (int k = 0; k < 4; ++k) {
                if (k < KS) {
                    mls[k] = *(const float2*)(mlW + ((size_t)(blkbase + k) * 64 + tid) * 2);
                    M = fmaxf(M, mls[k].x);
                }
            }
            float L = m0f * __expf(s0 - M);
            #pragma unroll
            for (int k = 0; k < 4; ++k)
                if (k < KS) L += mls[k].y * __expf(mls[k].x - M);
            float Li = 1.f / L;
            #pragma unroll
            for (int k = 0; k < 4; ++k)
                if (k < KS) wgtL[k][tid] = __expf(mls[k].x - M) * Li;
        }
        pixnL[tid] = pix;
    }
    __syncthreads();

    float* ob = out + ((size_t)b * NC + ch * 64) * NPIX;
    const ushort* pb = partW + (size_t)blkbase * 8192 + ch * 4096;
    #pragma unroll
    for (int it = 0; it < 2; ++it) {
        int idx = it * 256 + tid;
        int c = idx >> 3, grp = idx & 7;          // c local 0..63, 8-slot group
        float v[8] = {0.f,0.f,0.f,0.f,0.f,0.f,0.f,0.f};
        #pragma unroll
        for (int k = 0; k < 4; ++k) {
            if (k < KS) {
                ushort u[8];
                *(int4*)u = *(const int4*)(pb + (size_t)k * 8192 + c * 64 + grp * 8);
                #pragma unroll
                for (int j = 0; j < 8; ++j)
                    v[j] = fmaf(__uint_as_float((unsigned)u[j] << 16),
                                wgtL[k][grp * 8 + j], v[j]);
            }
        }
        #pragma unroll
        for (int j = 0; j < 8; ++j) {
            int pix = pixnL[grp * 8 + j];
            if (pix >= 0) ob[(size_t)c * NPIX + pix] = v[j];
        }
    }
}

extern "C" void kernel_launch(void* const* d_in, const int* in_sizes, int n_in,
                              void* d_out, int out_size, void* d_ws, size_t ws_size,
                              hipStream_t stream) {
    const float* x    = (const float*)d_in[0];
    const float* mask = (const float*)d_in[1];
    char* ws = (char*)d_ws;
    const size_t MBy = 1024 * 1024;
    const size_t KBy = 1024;

    ushort* KnW = (ushort*)(ws);                      // 4 MB compact Kn
    ushort* QW  = (ushort*)(ws + 4 * MBy);            // 4 MB compact Q
    ushort* VtW = (ushort*)(ws + 8 * MBy);            // 4 MB compact V^T
    ushort* KcW = (ushort*)(ws + 12 * MBy);           // 4 MB compact K (dead after vt)

    size_t need4 = 12 * MBy + 4 * 4 * MBy + 1 * MBy;
    int KS = (ws_size >= need4) ? 4 : 2;
    ushort* partW = (ushort*)(ws + 12 * MBy);                       // KS*4 MB
    char* tail = ws + 12 * MBy + (size_t)KS * 4 * MBy;
    float* mlW    = (float*)(tail);                                  // 512 KB
    int*   prefBH = (int*)(tail + 512 * KBy);                        // 64 KB
    float* s0c    = (float*)(tail + 576 * KBy);                      // 64 KB
    int*   pixQ   = (int*)(tail + 640 * KBy);                        // 64 KB
    int*   cnts   = (int*)(tail + 704 * KBy);                        // 32 B

    sffa_scan <<<4,   1024, 0, stream>>>(mask, prefBH, cnts);
    sffa_prep <<<256, 256,  0, stream>>>(x, mask, prefBH, KnW, QW, KcW, s0c, pixQ);
    sffa_vt   <<<256, 256,  0, stream>>>(KcW, cnts, VtW);
    sffa_attn <<<4 * 64 * KS, 512, 0, stream>>>(KnW, QW, VtW, cnts, partW, mlW, KS);
    sffa_copy <<<512, 256,  0, stream>>>((const float4*)x, (float4*)d_out);
    sffa_comb <<<512, 256,  0, stream>>>(partW, mlW, s0c, pixQ, cnts,
                                         (float*)d_out, KS);
}

// Round 6
// 66.199 us; speedup vs baseline: 1.5013x; 1.0878x over previous
//
#include <hip/hip_runtime.h>
#include <hip/hip_bf16.h>

typedef __attribute__((ext_vector_type(8))) short bf16x8;
typedef __attribute__((ext_vector_type(4))) float f32x4;

#define NPIX 4096
#define NC   128
#define RS128 0.08838834764831845f   // 1/sqrt(128)

// ---------------- scan (blocks 0..3) + full copy out=x (blocks 4..259) ----------------
__global__ __launch_bounds__(1024) void sffa_scan_copy(
    const float* __restrict__ mask, const float4* __restrict__ x4,
    int* __restrict__ prefBH, int* __restrict__ cnts, float4* __restrict__ out4)
{
    __shared__ int wsum[16];
    const int tid = threadIdx.x;
    if (blockIdx.x >= 4) {
        // copy: 256 blocks * 1024 thr * 2 float4 = 524288 float4 = 8 MB elems
        const int i0 = ((int)blockIdx.x - 4) * 2048 + tid;
        out4[i0] = x4[i0];
        out4[i0 + 1024] = x4[i0 + 1024];
        return;
    }
    const int b = blockIdx.x;
    const int lane = tid & 63, w = tid >> 6;
    float4 mv = *(const float4*)(mask + (size_t)b * NPIX + tid * 4);
    int f0 = mv.x < 0.5f ? 0x10000 : 1;
    int f1 = mv.y < 0.5f ? 0x10000 : 1;
    int f2 = mv.z < 0.5f ? 0x10000 : 1;
    int f3 = mv.w < 0.5f ? 0x10000 : 1;
    int tot = f0 + f1 + f2 + f3;
    int sc = tot;
    #pragma unroll
    for (int d = 1; d < 64; d <<= 1) { int t = __shfl_up(sc, d); if (lane >= d) sc += t; }
    if (lane == 63) wsum[w] = sc;
    __syncthreads();
    if (w == 0) {
        int v = (lane < 16) ? wsum[lane] : 0;
        int s = v;
        #pragma unroll
        for (int d = 1; d < 16; d <<= 1) { int t = __shfl_up(s, d); if (lane >= d) s += t; }
        if (lane < 16) wsum[lane] = s - v;
    }
    __syncthreads();
    int base = wsum[w] + sc - tot;
    int e0 = base, e1 = e0 + f0, e2 = e1 + f1, e3 = e2 + f2;
    *(int4*)(prefBH + (size_t)b * NPIX + tid * 4) = make_int4(e0, e1, e2, e3);
    if (tid == 1023) {
        int total = e3 + f3;
        cnts[b * 2]     = total & 0xffff;   // cntK (background patches)
        cnts[b * 2 + 1] = total >> 16;      // cntQ (hole pixels)
    }
}

// ---------------- prep: compacted Kn/Q rows + DIRECT Vt columns + s0 + pixQ ----------------
__global__ __launch_bounds__(256) void sffa_prep(
    const float* __restrict__ x, const float* __restrict__ mask,
    const int* __restrict__ prefBH,
    ushort* __restrict__ KnW, ushort* __restrict__ QW, ushort* __restrict__ VtW,
    float* __restrict__ s0c, int* __restrict__ pixQ)
{
    __shared__ float xs[128][69];
    __shared__ float ms[64];
    __shared__ float rinv[64];
    __shared__ float ssum[64];
    __shared__ float2 part[4][64];
    __shared__ int se[64];
    __shared__ int bgn[64];
    __shared__ int tinfo[2];   // s0base, nbg
    const int tid = threadIdx.x;
    const int b = blockIdx.x >> 6, nblk = blockIdx.x & 63;
    const int n0 = nblk * 64;
    const float* xb = x + (size_t)b * NC * NPIX;

    #pragma unroll
    for (int it = 0; it < 8; ++it) {
        int e4 = it * 256 + tid;
        int c = e4 >> 4, n4 = (e4 & 15) * 4;
        float4 v = *(const float4*)(xb + (size_t)c * NPIX + n0 + n4);
        xs[c][n4+0] = v.x; xs[c][n4+1] = v.y; xs[c][n4+2] = v.z; xs[c][n4+3] = v.w;
    }
    if (tid < 16) {
        float4 mv = *(const float4*)(mask + (size_t)b * NPIX + n0 + tid * 4);
        ms[tid*4+0] = mv.x; ms[tid*4+1] = mv.y; ms[tid*4+2] = mv.z; ms[tid*4+3] = mv.w;
    }
    if (tid >= 192) {
        int j = tid - 192;
        se[j] = prefBH[(size_t)b * NPIX + n0 + j];
    }
    __syncthreads();
    {
        int p = tid & 63, qd = tid >> 6;
        float m = ms[p];
        float s2 = 0.f, s1 = 0.f;
        #pragma unroll
        for (int i = 0; i < 32; ++i) {
            float xv = xs[qd*32 + i][p];
            float k = fmaf(xv, m, 1e-7f);
            s2 = fmaf(k, k, s2);
            s1 += xv;
        }
        part[qd][p] = make_float2(s2, s1);
    }
    __syncthreads();
    if (tid < 64) {
        float2 t0 = part[0][tid], t1 = part[1][tid], t2 = part[2][tid], t3 = part[3][tid];
        rinv[tid] = rsqrtf(t0.x + t1.x + t2.x + t3.x);
        ssum[tid] = (t0.y + t1.y + t2.y + t3.y) * RS128;
    }
    __syncthreads();
    // Kn & Q compacted rows, coalesced
    #pragma unroll
    for (int it = 0; it < 16; ++it) {
        int e2 = it * 256 + tid;
        int n = e2 >> 6, cp = (e2 & 63) * 2;
        int pe = se[n];
        float x0 = xs[cp][n], x1 = xs[cp+1][n];
        if (ms[n] > 0.5f) {
            int slot = pe & 0xffff;
            float k0 = x0 + 1e-7f, k1 = x1 + 1e-7f;
            float r = rinv[n];
            __hip_bfloat162 kn;
            kn.x = __float2bfloat16(k0 * r); kn.y = __float2bfloat16(k1 * r);
            *(__hip_bfloat162*)(KnW + ((size_t)b * NPIX + slot) * NC + cp) = kn;
        } else {
            int slot = pe >> 16;
            __hip_bfloat162 q;
            q.x = __float2bfloat16(x0); q.y = __float2bfloat16(x1);
            *(__hip_bfloat162*)(QW + ((size_t)b * NPIX + slot) * NC + cp) = q;
        }
    }
    if (tid < 64) {
        if (ms[tid] < 0.5f) {
            int slot = se[tid] >> 16;
            s0c [(size_t)b * NPIX + slot] = ssum[tid];
            pixQ[(size_t)b * NPIX + slot] = n0 + tid;
        } else {
            bgn[(se[tid] & 0xffff) - (se[0] & 0xffff)] = tid;
        }
    }
    if (tid == 0) {
        tinfo[0] = se[0] & 0xffff;
        tinfo[1] = (se[63] & 0xffff) + (ms[63] > 0.5f ? 1 : 0) - (se[0] & 0xffff);
    }
    __syncthreads();
    // Vt[c][slot] direct: bg slots of this tile are contiguous [s0b, s0b+nbg)
    {
        const int s0b = tinfo[0], nbg = tinfo[1];
        const int j = tid & 63, cg = tid >> 6;     // lane j = bg index, 4 c-groups
        if (j < nbg) {
            int n = bgn[j];
            ushort* vcol = VtW + (size_t)b * NC * NPIX + s0b + j;
            #pragma unroll
            for (int cc = 0; cc < 32; ++cc) {
                int c = cg * 32 + cc;
                __hip_bfloat16 h = __float2bfloat16(xs[c][n] + 1e-7f);
                vcol[(size_t)c * NPIX] = *(ushort*)&h;
            }
        }
    }
}

// ---------------- flash attention over compacted keys/queries (unchanged core) ----------------
#define L_BUF 32768
#define L_P   65536
#define L_ML  75776
#define L_SZ  76800

__global__ __launch_bounds__(512, 4) void sffa_attn(
    const ushort* __restrict__ KnW, const ushort* __restrict__ QW,
    const ushort* __restrict__ VtW, const int* __restrict__ cnts,
    ushort* __restrict__ partW, float* __restrict__ mlW, int KS)
{
    __shared__ __align__(16) char smem[L_SZ];
    const int tid  = threadIdx.x;
    const int w = tid >> 6, lane = tid & 63;
    const int l15 = lane & 15, g = lane >> 4;
    const int nwg = gridDim.x;
    const int bx = ((int)blockIdx.x & 7) * (nwg >> 3) + ((int)blockIdx.x >> 3);
    const int per = 64 * KS;
    const int b = bx / per;
    const int rem = bx - b * per;
    const int qblk = rem / KS, ks = rem - (rem / KS) * KS;
    const int q0 = qblk * 64;
    const int cntK = cnts[b * 2], cntQ = cnts[b * 2 + 1];
    if (q0 >= cntQ) return;
    const int blk = (b * 64 + qblk) * KS + ks;

    const int nk64 = (cntK + 63) >> 6;
    const int tpk  = (nk64 + KS - 1) / KS;
    const int t0   = ks * tpk;
    const int t1   = min(t0 + tpk, nk64);
    const int NTK  = t1 - t0;

    if (NTK <= 0) {
        unsigned* pz = (unsigned*)(partW + (size_t)blk * 8192);
        #pragma unroll
        for (int i = 0; i < 8; ++i) pz[i * 512 + tid] = 0u;
        if (tid < 64)
            *(float2*)(mlW + ((size_t)blk * 64 + tid) * 2) = make_float2(-1e30f, 0.f);
        return;
    }

    const int half = w >> 2;
    const int wq   = w & 3;
    const int kbase = t0 * 64;

    const ushort* Knb = KnW + (size_t)b * NPIX * NC;
    const ushort* Qb  = QW  + (size_t)b * NPIX * NC + (size_t)q0 * NC;
    const ushort* Vtb = VtW + (size_t)b * NC * NPIX;

    // ---- stage Q tile, read q-fragments ----
    #pragma unroll
    for (int it = 0; it < 2; ++it) {
        int L = (it * 512 + tid) * 16;
        int row = L >> 8, col = L & 255;
        int4 v = *(const int4*)((const char*)Qb + L);
        *(int4*)(smem + row * 256 + (col ^ ((row & 15) << 4))) = v;
    }
    __syncthreads();
    bf16x8 qf[4];
    {
        int qrow = wq * 16 + l15;
        #pragma unroll
        for (int kc = 0; kc < 4; ++kc)
            qf[kc] = *(const bf16x8*)(smem + qrow * 256 + ((64*kc + 16*g) ^ (l15 << 4)));
    }
    __syncthreads();

    const int kOff = (tid >> 4) * 256 + (((tid & 15) * 16) ^ (((tid >> 4) & 15) << 4));
    const int cV = tid >> 3, sV = tid & 7;
    const int vOff = cV * 128 + ((sV * 16) ^ ((cV & 7) << 4));
    const int4* kgbase = (const int4*)(Knb + (size_t)kbase * NC);
    const ushort* vgbase = Vtb + (size_t)cV * NPIX + kbase + sV * 8;

    int4 pr0, pr1, pr2, pr3;
    pr0 = kgbase[tid]; pr1 = kgbase[512 + tid];
    pr2 = *(const int4*)(vgbase);
    pr3 = *(const int4*)(vgbase + (size_t)64 * NPIX);
    {
        char* base = smem;
        *(int4*)(base + kOff) = pr0;
        *(int4*)(base + kOff + 8192) = pr1;
        *(int4*)(base + 16384 + vOff) = pr2;
        *(int4*)(base + 16384 + vOff + 8192) = pr3;
    }
    if (NTK > 1) {
        pr0 = kgbase[1024 + tid]; pr1 = kgbase[1536 + tid];
        pr2 = *(const int4*)(vgbase + 64);
        pr3 = *(const int4*)(vgbase + (size_t)64 * NPIX + 64);
    }
    __syncthreads();

    f32x4 acc[8];
    const f32x4 fzero = {0.f, 0.f, 0.f, 0.f};
    #pragma unroll
    for (int i = 0; i < 8; ++i) acc[i] = fzero;
    float mrun = -1e30f, lrun = 0.f;
    char* Pw = smem + L_P + w * 1280;

    for (int kt = 0; kt < NTK; ++kt) {
        if (kt + 1 < NTK) {
            char* base = smem + ((kt + 1) & 1) * L_BUF;
            *(int4*)(base + kOff) = pr0;
            *(int4*)(base + kOff + 8192) = pr1;
            *(int4*)(base + 16384 + vOff) = pr2;
            *(int4*)(base + 16384 + vOff + 8192) = pr3;
        }
        if (kt + 2 < NTK) {
            pr0 = kgbase[(kt + 2) * 1024 + tid];
            pr1 = kgbase[(kt + 2) * 1024 + 512 + tid];
            pr2 = *(const int4*)(vgbase + (kt + 2) * 64);
            pr3 = *(const int4*)(vgbase + (size_t)64 * NPIX + (kt + 2) * 64);
        }
        char* bb = smem + (kt & 1) * L_BUF;
        f32x4 sa0 = fzero, sa1 = fzero;
        {
            const char* rb0 = bb + (half * 32 + l15) * 256;
            const char* rb1 = rb0 + 4096;
            const int sw = l15 << 4;
            __builtin_amdgcn_s_setprio(1);
            #pragma unroll
            for (int kc = 0; kc < 4; ++kc) {
                int off = (64 * kc + 16 * g) ^ sw;
                bf16x8 a0 = *(const bf16x8*)(rb0 + off);
                bf16x8 a1 = *(const bf16x8*)(rb1 + off);
                sa0 = __builtin_amdgcn_mfma_f32_16x16x32_bf16(a0, qf[kc], sa0, 0, 0, 0);
                sa1 = __builtin_amdgcn_mfma_f32_16x16x32_bf16(a1, qf[kc], sa1, 0, 0, 0);
            }
            __builtin_amdgcn_s_setprio(0);
        }
        {
            int kg0 = (t0 + kt) * 64;
            if (kg0 + 64 > cntK) {
                int kb = cntK - kg0;
                int kr = half * 32 + 4 * g;
                #pragma unroll
                for (int r = 0; r < 4; ++r) {
                    if (kr + r >= kb)      sa0[r] = -3e38f;
                    if (kr + 16 + r >= kb) sa1[r] = -3e38f;
                }
            }
        }
        float tmax = fmaxf(fmaxf(fmaxf(sa0[0], sa0[1]), fmaxf(sa0[2], sa0[3])),
                           fmaxf(fmaxf(sa1[0], sa1[1]), fmaxf(sa1[2], sa1[3])));
        tmax = fmaxf(tmax, __shfl_xor(tmax, 16));
        tmax = fmaxf(tmax, __shfl_xor(tmax, 32));
        bool grow = !__all(tmax <= mrun + 8.f);
        float mnew = grow ? fmaxf(mrun, tmax) : mrun;
        float p0[4], p1[4];
        float ts = 0.f;
        #pragma unroll
        for (int r = 0; r < 4; ++r) { p0[r] = __expf(sa0[r] - mnew); ts += p0[r]; }
        #pragma unroll
        for (int r = 0; r < 4; ++r) { p1[r] = __expf(sa1[r] - mnew); ts += p1[r]; }
        ts += __shfl_xor(ts, 16);
        ts += __shfl_xor(ts, 32);
        if (grow) {
            float sc = __expf(mrun - mnew);
            lrun = lrun * sc + ts;
            float scr[4];
            #pragma unroll
            for (int r = 0; r < 4; ++r) scr[r] = __shfl(sc, 4 * g + r);
            #pragma unroll
            for (int ct = 0; ct < 8; ++ct) {
                acc[ct][0] *= scr[0]; acc[ct][1] *= scr[1];
                acc[ct][2] *= scr[2]; acc[ct][3] *= scr[3];
            }
            mrun = mnew;
        } else {
            lrun += ts;
        }
        union { __hip_bfloat162 h; unsigned u; } ua0, ua1, ub0, ub1;
        ua0.h.x = __float2bfloat16(p0[0]); ua0.h.y = __float2bfloat16(p0[1]);
        ua1.h.x = __float2bfloat16(p0[2]); ua1.h.y = __float2bfloat16(p0[3]);
        ub0.h.x = __float2bfloat16(p1[0]); ub0.h.y = __float2bfloat16(p1[1]);
        ub1.h.x = __float2bfloat16(p1[2]); ub1.h.y = __float2bfloat16(p1[3]);
        *(int2*)(Pw + l15 * 80 +      8 * g) = make_int2((int)ua0.u, (int)ua1.u);
        *(int2*)(Pw + l15 * 80 + 32 + 8 * g) = make_int2((int)ub0.u, (int)ub1.u);
        bf16x8 pf = *(const bf16x8*)(Pw + l15 * 80 + 16 * g);
        {
            const char* vb = bb + 16384;
            __builtin_amdgcn_s_setprio(1);
            #pragma unroll
            for (int ct = 0; ct < 8; ++ct) {
                int c = 16 * ct + l15;
                bf16x8 vf = *(const bf16x8*)(vb + c * 128 +
                                             ((64 * half + 16 * g) ^ ((c & 7) << 4)));
                acc[ct] = __builtin_amdgcn_mfma_f32_16x16x32_bf16(pf, vf, acc[ct], 0, 0, 0);
            }
            __builtin_amdgcn_s_setprio(0);
        }
        __syncthreads();
    }

    float* ma = (float*)(smem + L_ML);
    float* la = ma + 64; float* mb = la + 64; float* lb = mb + 64;
    const int q = wq * 16 + l15;
    if (g == 0) {
        if (half == 0) { ma[q] = mrun; la[q] = lrun; }
        else           { mb[q] = mrun; lb[q] = lrun; }
    }
    __syncthreads();
    float* agg = (float*)smem;
    {
        float mstar = fmaxf(ma[q], mb[q]);
        float f = __expf(mrun - mstar);
        float fr[4];
        #pragma unroll
        for (int r = 0; r < 4; ++r) fr[r] = __shfl(f, 4 * g + r);
        if (half == 1) {
            #pragma unroll
            for (int ct = 0; ct < 8; ++ct) {
                int c = 16 * ct + l15;
                #pragma unroll
                for (int r = 0; r < 4; ++r)
                    agg[c * 68 + wq * 16 + 4 * g + r] = acc[ct][r] * fr[r];
            }
        }
        __syncthreads();
        if (half == 0) {
            #pragma unroll
            for (int ct = 0; ct < 8; ++ct) {
                int c = 16 * ct + l15;
                #pragma unroll
                for (int r = 0; r < 4; ++r) {
                    int idx = c * 68 + wq * 16 + 4 * g + r;
                    agg[idx] = acc[ct][r] * fr[r] + agg[idx];
                }
            }
        }
    }
    __syncthreads();
    if (tid < 64) {
        float M = fmaxf(ma[tid], mb[tid]);
        float ls = la[tid] * __expf(ma[tid] - M) + lb[tid] * __expf(mb[tid] - M);
        *(float2*)(mlW + ((size_t)blk * 64 + tid) * 2) = make_float2(M, ls);
    }
    ushort* pdst = partW + (size_t)blk * 8192;
    #pragma unroll
    for (int it = 0; it < 8; ++it) {
        int idx = it * 512 + tid;
        int c = idx >> 5, n2 = (idx & 31) * 2;
        __hip_bfloat162 h;
        h.x = __float2bfloat16(agg[c * 68 + n2]);
        h.y = __float2bfloat16(agg[c * 68 + n2 + 1]);
        *(__hip_bfloat162*)(pdst + c * 64 + n2) = h;
    }
}

// ---------------- comb: slot-space vectorized combine + scatter (4-way c-split) ----------------
__global__ __launch_bounds__(256) void sffa_comb(
    const ushort* __restrict__ partW, const float* __restrict__ mlW,
    const float* __restrict__ s0c, const int* __restrict__ pixQ,
    const int* __restrict__ cnts, float* __restrict__ out, int KS)
{
    __shared__ float wgtL[4][64];
    __shared__ int pixnL[64];
    const int tid = threadIdx.x;
    const int bx = blockIdx.x;
    const int b = bx >> 8, qb = (bx >> 2) & 63, ch = bx & 3;
    const int cntK = cnts[b * 2], cntQ = cnts[b * 2 + 1];
    if (qb * 64 >= cntQ) return;
    const int blkbase = (b * 64 + qb) * KS;
    const float m0f = (float)(NPIX - cntK);

    if (tid < 64) {
        int slot = qb * 64 + tid;
        int pix = -1;
        if (slot < cntQ) {
            pix = pixQ[(size_t)b * NPIX + slot];
            float s0 = s0c[(size_t)b * NPIX + slot];
            float M = s0;
            float2 mls[4];
            #pragma unroll
            for (int k = 0; k < 4; ++k) {
                if (k < KS) {
                    mls[k] = *(const float2*)(mlW + ((size_t)(blkbase + k) * 64 + tid) * 2);
                    M = fmaxf(M, mls[k].x);
                }
            }
            float L = m0f * __expf(s0 - M);
            #pragma unroll
            for (int k = 0; k < 4; ++k)
                if (k < KS) L += mls[k].y * __expf(mls[k].x - M);
            float Li = 1.f / L;
            #pragma unroll
            for (int k = 0; k < 4; ++k)
                if (k < KS) wgtL[k][tid] = __expf(mls[k].x - M) * Li;
        }
        pixnL[tid] = pix;
    }
    __syncthreads();

    float* ob = out + (size_t)b * NC * NPIX;
    const ushort* pb = partW + (size_t)blkbase * 8192;
    {
        int cl = tid >> 3, grp = tid & 7;       // 32 c per chunk, 8-slot groups
        int c = ch * 32 + cl;
        float v[8] = {0.f,0.f,0.f,0.f,0.f,0.f,0.f,0.f};
        #pragma unroll
        for (int k = 0; k < 4; ++k) {
            if (k < KS) {
                ushort u[8];
                *(int4*)u = *(const int4*)(pb + (size_t)k * 8192 + c * 64 + grp * 8);
                #pragma unroll
                for (int j = 0; j < 8; ++j)
                    v[j] = fmaf(__uint_as_float((unsigned)u[j] << 16),
                                wgtL[k][grp * 8 + j], v[j]);
            }
        }
        #pragma unroll
        for (int j = 0; j < 8; ++j) {
            int pix = pixnL[grp * 8 + j];
            if (pix >= 0) ob[(size_t)c * NPIX + pix] = v[j];
        }
    }
}

extern "C" void kernel_launch(void* const* d_in, const int* in_sizes, int n_in,
                              void* d_out, int out_size, void* d_ws, size_t ws_size,
                              hipStream_t stream) {
    const float* x    = (const float*)d_in[0];
    const float* mask = (const float*)d_in[1];
    char* ws = (char*)d_ws;
    const size_t MBy = 1024 * 1024;
    const size_t KBy = 1024;

    ushort* KnW = (ushort*)(ws);                      // 4 MB compact Kn
    ushort* QW  = (ushort*)(ws + 4 * MBy);            // 4 MB compact Q
    ushort* VtW = (ushort*)(ws + 8 * MBy);            // 4 MB compact V^T

    size_t need4 = 12 * MBy + 4 * 4 * MBy + 1 * MBy;
    int KS = (ws_size >= need4) ? 4 : 2;
    ushort* partW = (ushort*)(ws + 12 * MBy);                       // KS*4 MB
    char* tail = ws + 12 * MBy + (size_t)KS * 4 * MBy;
    float* mlW    = (float*)(tail);                                  // 512 KB
    int*   prefBH = (int*)(tail + 512 * KBy);                        // 64 KB
    float* s0c    = (float*)(tail + 576 * KBy);                      // 64 KB
    int*   pixQ   = (int*)(tail + 640 * KBy);                        // 64 KB
    int*   cnts   = (int*)(tail + 704 * KBy);                        // 32 B

    sffa_scan_copy<<<260, 1024, 0, stream>>>(mask, (const float4*)x, prefBH, cnts,
                                             (float4*)d_out);
    sffa_prep <<<256, 256,  0, stream>>>(x, mask, prefBH, KnW, QW, VtW, s0c, pixQ);
    sffa_attn <<<4 * 64 * KS, 512, 0, stream>>>(KnW, QW, VtW, cnts, partW, mlW, KS);
    sffa_comb <<<4 * 64 * 4, 256, 0, stream>>>(partW, mlW, s0c, pixQ, cnts,
                                               (float*)d_out, KS);
}

// Round 7
// 56.468 us; speedup vs baseline: 1.7600x; 1.1723x over previous
//
#include <hip/hip_runtime.h>
#include <hip/hip_bf16.h>

typedef __attribute__((ext_vector_type(8))) short bf16x8;
typedef __attribute__((ext_vector_type(4))) float f32x4;

#define NPIX 4096
#define NC   128
#define RS128 0.08838834764831845f   // 1/sqrt(128)

// ---------------- scan (blocks 0..3) + full copy out=x (blocks 4..259) ----------------
__global__ __launch_bounds__(1024) void sffa_scan_copy(
    const float* __restrict__ mask, const float4* __restrict__ x4,
    int* __restrict__ prefBH, int* __restrict__ cnts, float4* __restrict__ out4)
{
    __shared__ int wsum[16];
    const int tid = threadIdx.x;
    if (blockIdx.x >= 4) {
        const int i0 = ((int)blockIdx.x - 4) * 2048 + tid;
        out4[i0] = x4[i0];
        out4[i0 + 1024] = x4[i0 + 1024];
        return;
    }
    const int b = blockIdx.x;
    const int lane = tid & 63, w = tid >> 6;
    float4 mv = *(const float4*)(mask + (size_t)b * NPIX + tid * 4);
    int f0 = mv.x < 0.5f ? 0x10000 : 1;
    int f1 = mv.y < 0.5f ? 0x10000 : 1;
    int f2 = mv.z < 0.5f ? 0x10000 : 1;
    int f3 = mv.w < 0.5f ? 0x10000 : 1;
    int tot = f0 + f1 + f2 + f3;
    int sc = tot;
    #pragma unroll
    for (int d = 1; d < 64; d <<= 1) { int t = __shfl_up(sc, d); if (lane >= d) sc += t; }
    if (lane == 63) wsum[w] = sc;
    __syncthreads();
    if (w == 0) {
        int v = (lane < 16) ? wsum[lane] : 0;
        int s = v;
        #pragma unroll
        for (int d = 1; d < 16; d <<= 1) { int t = __shfl_up(s, d); if (lane >= d) s += t; }
        if (lane < 16) wsum[lane] = s - v;
    }
    __syncthreads();
    int base = wsum[w] + sc - tot;
    int e0 = base, e1 = e0 + f0, e2 = e1 + f1, e3 = e2 + f2;
    *(int4*)(prefBH + (size_t)b * NPIX + tid * 4) = make_int4(e0, e1, e2, e3);
    if (tid == 1023) {
        int total = e3 + f3;
        cnts[b * 2]     = total & 0xffff;   // cntK (background patches)
        cnts[b * 2 + 1] = total >> 16;      // cntQ (hole pixels)
    }
}

// ---------------- prep (1024 thr): compacted Kn/Q rows + direct Vt + s0 + pixQ ----------------
__global__ __launch_bounds__(1024) void sffa_prep(
    const float* __restrict__ x, const float* __restrict__ mask,
    const int* __restrict__ prefBH,
    ushort* __restrict__ KnW, ushort* __restrict__ QW, ushort* __restrict__ VtW,
    float* __restrict__ s0c, int* __restrict__ pixQ)
{
    __shared__ float xs[128][69];
    __shared__ float ms[64];
    __shared__ float rinv[64];
    __shared__ float ssum[64];
    __shared__ float2 part[16][64];
    __shared__ int se[64];
    __shared__ int bgn[64];
    __shared__ int tinfo[2];   // s0base, nbg
    const int tid = threadIdx.x;
    const int b = blockIdx.x >> 6, nblk = blockIdx.x & 63;
    const int n0 = nblk * 64;
    const float* xb = x + (size_t)b * NC * NPIX;

    #pragma unroll
    for (int it = 0; it < 2; ++it) {
        int e4 = it * 1024 + tid;
        int c = e4 >> 4, n4 = (e4 & 15) * 4;
        float4 v = *(const float4*)(xb + (size_t)c * NPIX + n0 + n4);
        xs[c][n4+0] = v.x; xs[c][n4+1] = v.y; xs[c][n4+2] = v.z; xs[c][n4+3] = v.w;
    }
    if (tid < 16) {
        float4 mv = *(const float4*)(mask + (size_t)b * NPIX + n0 + tid * 4);
        ms[tid*4+0] = mv.x; ms[tid*4+1] = mv.y; ms[tid*4+2] = mv.z; ms[tid*4+3] = mv.w;
    }
    if (tid >= 960) {
        int j = tid - 960;
        se[j] = prefBH[(size_t)b * NPIX + n0 + j];
    }
    __syncthreads();
    {
        int p = tid & 63, qd = tid >> 6;    // 16 groups of 8 channels
        float m = ms[p];
        float s2 = 0.f, s1 = 0.f;
        #pragma unroll
        for (int i = 0; i < 8; ++i) {
            float xv = xs[qd*8 + i][p];
            float k = fmaf(xv, m, 1e-7f);
            s2 = fmaf(k, k, s2);
            s1 += xv;
        }
        part[qd][p] = make_float2(s2, s1);
    }
    __syncthreads();
    if (tid < 64) {
        float s2 = 0.f, s1 = 0.f;
        #pragma unroll
        for (int k = 0; k < 16; ++k) { float2 t = part[k][tid]; s2 += t.x; s1 += t.y; }
        rinv[tid] = rsqrtf(s2);
        ssum[tid] = s1 * RS128;
    }
    __syncthreads();
    // Kn & Q compacted rows, coalesced
    #pragma unroll
    for (int it = 0; it < 4; ++it) {
        int e2 = it * 1024 + tid;
        int n = e2 >> 6, cp = (e2 & 63) * 2;
        int pe = se[n];
        float x0 = xs[cp][n], x1 = xs[cp+1][n];
        if (ms[n] > 0.5f) {
            int slot = pe & 0xffff;
            float k0 = x0 + 1e-7f, k1 = x1 + 1e-7f;
            float r = rinv[n];
            __hip_bfloat162 kn;
            kn.x = __float2bfloat16(k0 * r); kn.y = __float2bfloat16(k1 * r);
            *(__hip_bfloat162*)(KnW + ((size_t)b * NPIX + slot) * NC + cp) = kn;
        } else {
            int slot = pe >> 16;
            __hip_bfloat162 q;
            q.x = __float2bfloat16(x0); q.y = __float2bfloat16(x1);
            *(__hip_bfloat162*)(QW + ((size_t)b * NPIX + slot) * NC + cp) = q;
        }
    }
    if (tid < 64) {
        if (ms[tid] < 0.5f) {
            int slot = se[tid] >> 16;
            s0c [(size_t)b * NPIX + slot] = ssum[tid];
            pixQ[(size_t)b * NPIX + slot] = n0 + tid;
        } else {
            bgn[(se[tid] & 0xffff) - (se[0] & 0xffff)] = tid;
        }
    }
    if (tid == 0) {
        tinfo[0] = se[0] & 0xffff;
        tinfo[1] = (se[63] & 0xffff) + (ms[63] > 0.5f ? 1 : 0) - (se[0] & 0xffff);
    }
    __syncthreads();
    // Vt[c][slot] direct: bg slots of this tile are contiguous [s0b, s0b+nbg)
    {
        const int s0b = tinfo[0], nbg = tinfo[1];
        const int j = tid & 63, cg = tid >> 6;     // lane j = bg index, 16 c-groups of 8
        if (j < nbg) {
            int n = bgn[j];
            ushort* vcol = VtW + (size_t)b * NC * NPIX + s0b + j;
            #pragma unroll
            for (int cc = 0; cc < 8; ++cc) {
                int c = cg * 8 + cc;
                __hip_bfloat16 h = __float2bfloat16(xs[c][n] + 1e-7f);
                vcol[(size_t)c * NPIX] = *(ushort*)&h;
            }
        }
    }
}

// ---------------- flash attention over compacted keys/queries (no XCD swizzle!) ----------------
#define L_BUF 32768
#define L_P   65536
#define L_ML  75776
#define L_SZ  76800

__global__ __launch_bounds__(512, 4) void sffa_attn(
    const ushort* __restrict__ KnW, const ushort* __restrict__ QW,
    const ushort* __restrict__ VtW, const int* __restrict__ cnts,
    ushort* __restrict__ partW, float* __restrict__ mlW, int KS)
{
    __shared__ __align__(16) char smem[L_SZ];
    const int tid  = threadIdx.x;
    const int w = tid >> 6, lane = tid & 63;
    const int l15 = lane & 15, g = lane >> 4;
    // NO XCD swizzle: with compaction, qblk>=cntQ/64 blocks early-exit; the swizzle
    // concentrated all ACTIVE blocks onto the even XCDs (half the GPU idle).
    const int bx = (int)blockIdx.x;
    const int per = 64 * KS;
    const int b = bx / per;
    const int rem = bx - b * per;
    const int qblk = rem / KS, ks = rem - (rem / KS) * KS;
    const int q0 = qblk * 64;
    const int cntK = cnts[b * 2], cntQ = cnts[b * 2 + 1];
    if (q0 >= cntQ) return;
    const int blk = (b * 64 + qblk) * KS + ks;

    const int nk64 = (cntK + 63) >> 6;
    const int tpk  = (nk64 + KS - 1) / KS;
    const int t0   = ks * tpk;
    const int t1   = min(t0 + tpk, nk64);
    const int NTK  = t1 - t0;

    if (NTK <= 0) {
        unsigned* pz = (unsigned*)(partW + (size_t)blk * 8192);
        #pragma unroll
        for (int i = 0; i < 8; ++i) pz[i * 512 + tid] = 0u;
        if (tid < 64)
            *(float2*)(mlW + ((size_t)blk * 64 + tid) * 2) = make_float2(-1e30f, 0.f);
        return;
    }

    const int half = w >> 2;
    const int wq   = w & 3;
    const int kbase = t0 * 64;

    const ushort* Knb = KnW + (size_t)b * NPIX * NC;
    const ushort* Qb  = QW  + (size_t)b * NPIX * NC + (size_t)q0 * NC;
    const ushort* Vtb = VtW + (size_t)b * NC * NPIX;

    // ---- stage Q tile, read q-fragments ----
    #pragma unroll
    for (int it = 0; it < 2; ++it) {
        int L = (it * 512 + tid) * 16;
        int row = L >> 8, col = L & 255;
        int4 v = *(const int4*)((const char*)Qb + L);
        *(int4*)(smem + row * 256 + (col ^ ((row & 15) << 4))) = v;
    }
    __syncthreads();
    bf16x8 qf[4];
    {
        int qrow = wq * 16 + l15;
        #pragma unroll
        for (int kc = 0; kc < 4; ++kc)
            qf[kc] = *(const bf16x8*)(smem + qrow * 256 + ((64*kc + 16*g) ^ (l15 << 4)));
    }
    __syncthreads();

    const int kOff = (tid >> 4) * 256 + (((tid & 15) * 16) ^ (((tid >> 4) & 15) << 4));
    const int cV = tid >> 3, sV = tid & 7;
    const int vOff = cV * 128 + ((sV * 16) ^ ((cV & 7) << 4));
    const int4* kgbase = (const int4*)(Knb + (size_t)kbase * NC);
    const ushort* vgbase = Vtb + (size_t)cV * NPIX + kbase + sV * 8;

    int4 pr0, pr1, pr2, pr3;
    pr0 = kgbase[tid]; pr1 = kgbase[512 + tid];
    pr2 = *(const int4*)(vgbase);
    pr3 = *(const int4*)(vgbase + (size_t)64 * NPIX);
    {
        char* base = smem;
        *(int4*)(base + kOff) = pr0;
        *(int4*)(base + kOff + 8192) = pr1;
        *(int4*)(base + 16384 + vOff) = pr2;
        *(int4*)(base + 16384 + vOff + 8192) = pr3;
    }
    if (NTK > 1) {
        pr0 = kgbase[1024 + tid]; pr1 = kgbase[1536 + tid];
        pr2 = *(const int4*)(vgbase + 64);
        pr3 = *(const int4*)(vgbase + (size_t)64 * NPIX + 64);
    }
    __syncthreads();

    f32x4 acc[8];
    const f32x4 fzero = {0.f, 0.f, 0.f, 0.f};
    #pragma unroll
    for (int i = 0; i < 8; ++i) acc[i] = fzero;
    float mrun = -1e30f, lrun = 0.f;
    char* Pw = smem + L_P + w * 1280;

    for (int kt = 0; kt < NTK; ++kt) {
        if (kt + 1 < NTK) {
            char* base = smem + ((kt + 1) & 1) * L_BUF;
            *(int4*)(base + kOff) = pr0;
            *(int4*)(base + kOff + 8192) = pr1;
            *(int4*)(base + 16384 + vOff) = pr2;
            *(int4*)(base + 16384 + vOff + 8192) = pr3;
        }
        if (kt + 2 < NTK) {
            pr0 = kgbase[(kt + 2) * 1024 + tid];
            pr1 = kgbase[(kt + 2) * 1024 + 512 + tid];
            pr2 = *(const int4*)(vgbase + (kt + 2) * 64);
            pr3 = *(const int4*)(vgbase + (size_t)64 * NPIX + (kt + 2) * 64);
        }
        char* bb = smem + (kt & 1) * L_BUF;
        f32x4 sa0 = fzero, sa1 = fzero;
        {
            const char* rb0 = bb + (half * 32 + l15) * 256;
            const char* rb1 = rb0 + 4096;
            const int sw = l15 << 4;
            __builtin_amdgcn_s_setprio(1);
            #pragma unroll
            for (int kc = 0; kc < 4; ++kc) {
                int off = (64 * kc + 16 * g) ^ sw;
                bf16x8 a0 = *(const bf16x8*)(rb0 + off);
                bf16x8 a1 = *(const bf16x8*)(rb1 + off);
                sa0 = __builtin_amdgcn_mfma_f32_16x16x32_bf16(a0, qf[kc], sa0, 0, 0, 0);
                sa1 = __builtin_amdgcn_mfma_f32_16x16x32_bf16(a1, qf[kc], sa1, 0, 0, 0);
            }
            __builtin_amdgcn_s_setprio(0);
        }
        {
            int kg0 = (t0 + kt) * 64;
            if (kg0 + 64 > cntK) {
                int kb = cntK - kg0;
                int kr = half * 32 + 4 * g;
                #pragma unroll
                for (int r = 0; r < 4; ++r) {
                    if (kr + r >= kb)      sa0[r] = -3e38f;
                    if (kr + 16 + r >= kb) sa1[r] = -3e38f;
                }
            }
        }
        float tmax = fmaxf(fmaxf(fmaxf(sa0[0], sa0[1]), fmaxf(sa0[2], sa0[3])),
                           fmaxf(fmaxf(sa1[0], sa1[1]), fmaxf(sa1[2], sa1[3])));
        tmax = fmaxf(tmax, __shfl_xor(tmax, 16));
        tmax = fmaxf(tmax, __shfl_xor(tmax, 32));
        bool grow = !__all(tmax <= mrun + 8.f);
        float mnew = grow ? fmaxf(mrun, tmax) : mrun;
        float p0[4], p1[4];
        float ts = 0.f;
        #pragma unroll
        for (int r = 0; r < 4; ++r) { p0[r] = __expf(sa0[r] - mnew); ts += p0[r]; }
        #pragma unroll
        for (int r = 0; r < 4; ++r) { p1[r] = __expf(sa1[r] - mnew); ts += p1[r]; }
        ts += __shfl_xor(ts, 16);
        ts += __shfl_xor(ts, 32);
        if (grow) {
            float sc = __expf(mrun - mnew);
            lrun = lrun * sc + ts;
            float scr[4];
            #pragma unroll
            for (int r = 0; r < 4; ++r) scr[r] = __shfl(sc, 4 * g + r);
            #pragma unroll
            for (int ct = 0; ct < 8; ++ct) {
                acc[ct][0] *= scr[0]; acc[ct][1] *= scr[1];
                acc[ct][2] *= scr[2]; acc[ct][3] *= scr[3];
            }
            mrun = mnew;
        } else {
            lrun += ts;
        }
        union { __hip_bfloat162 h; unsigned u; } ua0, ua1, ub0, ub1;
        ua0.h.x = __float2bfloat16(p0[0]); ua0.h.y = __float2bfloat16(p0[1]);
        ua1.h.x = __float2bfloat16(p0[2]); ua1.h.y = __float2bfloat16(p0[3]);
        ub0.h.x = __float2bfloat16(p1[0]); ub0.h.y = __float2bfloat16(p1[1]);
        ub1.h.x = __float2bfloat16(p1[2]); ub1.h.y = __float2bfloat16(p1[3]);
        *(int2*)(Pw + l15 * 80 +      8 * g) = make_int2((int)ua0.u, (int)ua1.u);
        *(int2*)(Pw + l15 * 80 + 32 + 8 * g) = make_int2((int)ub0.u, (int)ub1.u);
        bf16x8 pf = *(const bf16x8*)(Pw + l15 * 80 + 16 * g);
        {
            const char* vb = bb + 16384;
            __builtin_amdgcn_s_setprio(1);
            #pragma unroll
            for (int ct = 0; ct < 8; ++ct) {
                int c = 16 * ct + l15;
                bf16x8 vf = *(const bf16x8*)(vb + c * 128 +
                                             ((64 * half + 16 * g) ^ ((c & 7) << 4)));
                acc[ct] = __builtin_amdgcn_mfma_f32_16x16x32_bf16(pf, vf, acc[ct], 0, 0, 0);
            }
            __builtin_amdgcn_s_setprio(0);
        }
        __syncthreads();
    }

    float* ma = (float*)(smem + L_ML);
    float* la = ma + 64; float* mb = la + 64; float* lb = mb + 64;
    const int q = wq * 16 + l15;
    if (g == 0) {
        if (half == 0) { ma[q] = mrun; la[q] = lrun; }
        else           { mb[q] = mrun; lb[q] = lrun; }
    }
    __syncthreads();
    float* agg = (float*)smem;
    {
        float mstar = fmaxf(ma[q], mb[q]);
        float f = __expf(mrun - mstar);
        float fr[4];
        #pragma unroll
        for (int r = 0; r < 4; ++r) fr[r] = __shfl(f, 4 * g + r);
        if (half == 1) {
            #pragma unroll
            for (int ct = 0; ct < 8; ++ct) {
                int c = 16 * ct + l15;
                #pragma unroll
                for (int r = 0; r < 4; ++r)
                    agg[c * 68 + wq * 16 + 4 * g + r] = acc[ct][r] * fr[r];
            }
        }
        __syncthreads();
        if (half == 0) {
            #pragma unroll
            for (int ct = 0; ct < 8; ++ct) {
                int c = 16 * ct + l15;
                #pragma unroll
                for (int r = 0; r < 4; ++r) {
                    int idx = c * 68 + wq * 16 + 4 * g + r;
                    agg[idx] = acc[ct][r] * fr[r] + agg[idx];
                }
            }
        }
    }
    __syncthreads();
    if (tid < 64) {
        float M = fmaxf(ma[tid], mb[tid]);
        float ls = la[tid] * __expf(ma[tid] - M) + lb[tid] * __expf(mb[tid] - M);
        *(float2*)(mlW + ((size_t)blk * 64 + tid) * 2) = make_float2(M, ls);
    }
    ushort* pdst = partW + (size_t)blk * 8192;
    #pragma unroll
    for (int it = 0; it < 8; ++it) {
        int idx = it * 512 + tid;
        int c = idx >> 5, n2 = (idx & 31) * 2;
        __hip_bfloat162 h;
        h.x = __float2bfloat16(agg[c * 68 + n2]);
        h.y = __float2bfloat16(agg[c * 68 + n2 + 1]);
        *(__hip_bfloat162*)(pdst + c * 64 + n2) = h;
    }
}

// ---------------- comb: slot-space vectorized combine + scatter (4-way c-split) ----------------
__global__ __launch_bounds__(256) void sffa_comb(
    const ushort* __restrict__ partW, const float* __restrict__ mlW,
    const float* __restrict__ s0c, const int* __restrict__ pixQ,
    const int* __restrict__ cnts, float* __restrict__ out, int KS)
{
    __shared__ float wgtL[4][64];
    __shared__ int pixnL[64];
    const int tid = threadIdx.x;
    const int bx = blockIdx.x;
    const int b = bx >> 8, qb = (bx >> 2) & 63, ch = bx & 3;
    const int cntK = cnts[b * 2], cntQ = cnts[b * 2 + 1];
    if (qb * 64 >= cntQ) return;
    const int blkbase = (b * 64 + qb) * KS;
    const float m0f = (float)(NPIX - cntK);

    if (tid < 64) {
        int slot = qb * 64 + tid;
        int pix = -1;
        if (slot < cntQ) {
            pix = pixQ[(size_t)b * NPIX + slot];
            float s0 = s0c[(size_t)b * NPIX + slot];
            float M = s0;
            float2 mls[4];
            #pragma unroll
            for (int k = 0; k < 4; ++k) {
                if (k < KS) {
                    mls[k] = *(const float2*)(mlW + ((size_t)(blkbase + k) * 64 + tid) * 2);
                    M = fmaxf(M, mls[k].x);
                }
            }
            float L = m0f * __expf(s0 - M);
            #pragma unroll
            for (int k = 0; k < 4; ++k)
                if (k < KS) L += mls[k].y * __expf(mls[k].x - M);
            float Li = 1.f / L;
            #pragma unroll
            for (int k = 0; k < 4; ++k)
                if (k < KS) wgtL[k][tid] = __expf(mls[k].x - M) * Li;
        }
        pixnL[tid] = pix;
    }
    __syncthreads();

    float* ob = out + (size_t)b * NC * NPIX;
    const ushort* pb = partW + (size_t)blkbase * 8192;
    {
        int cl = tid >> 3, grp = tid & 7;       // 32 c per chunk, 8-slot groups
        int c = ch * 32 + cl;
        float v[8] = {0.f,0.f,0.f,0.f,0.f,0.f,0.f,0.f};
        #pragma unroll
        for (int k = 0; k < 4; ++k) {
            if (k < KS) {
                ushort u[8];
                *(int4*)u = *(const int4*)(pb + (size_t)k * 8192 + c * 64 + grp * 8);
                #pragma unroll
                for (int j = 0; j < 8; ++j)
                    v[j] = fmaf(__uint_as_float((unsigned)u[j] << 16),
                                wgtL[k][grp * 8 + j], v[j]);
            }
        }
        #pragma unroll
        for (int j = 0; j < 8; ++j) {
            int pix = pixnL[grp * 8 + j];
            if (pix >= 0) ob[(size_t)c * NPIX + pix] = v[j];
        }
    }
}

extern "C" void kernel_launch(void* const* d_in, const int* in_sizes, int n_in,
                              void* d_out, int out_size, void* d_ws, size_t ws_size,
                              hipStream_t stream) {
    const float* x    = (const float*)d_in[0];
    const float* mask = (const float*)d_in[1];
    char* ws = (char*)d_ws;
    const size_t MBy = 1024 * 1024;
    const size_t KBy = 1024;

    ushort* KnW = (ushort*)(ws);                      // 4 MB compact Kn
    ushort* QW  = (ushort*)(ws + 4 * MBy);            // 4 MB compact Q
    ushort* VtW = (ushort*)(ws + 8 * MBy);            // 4 MB compact V^T

    size_t need4 = 12 * MBy + 4 * 4 * MBy + 1 * MBy;
    int KS = (ws_size >= need4) ? 4 : 2;
    ushort* partW = (ushort*)(ws + 12 * MBy);                       // KS*4 MB
    char* tail = ws + 12 * MBy + (size_t)KS * 4 * MBy;
    float* mlW    = (float*)(tail);                                  // 512 KB
    int*   prefBH = (int*)(tail + 512 * KBy);                        // 64 KB
    float* s0c    = (float*)(tail + 576 * KBy);                      // 64 KB
    int*   pixQ   = (int*)(tail + 640 * KBy);                        // 64 KB
    int*   cnts   = (int*)(tail + 704 * KBy);                        // 32 B

    sffa_scan_copy<<<260, 1024, 0, stream>>>(mask, (const float4*)x, prefBH, cnts,
                                             (float4*)d_out);
    sffa_prep <<<256, 1024, 0, stream>>>(x, mask, prefBH, KnW, QW, VtW, s0c, pixQ);
    sffa_attn <<<4 * 64 * KS, 512, 0, stream>>>(KnW, QW, VtW, cnts, partW, mlW, KS);
    sffa_comb <<<4 * 64 * 4, 256, 0, stream>>>(partW, mlW, s0c, pixQ, cnts,
                                               (float*)d_out, KS);
}

// Round 8
// 53.376 us; speedup vs baseline: 1.8619x; 1.0579x over previous
//
#include <hip/hip_runtime.h>
#include <hip/hip_bf16.h>

typedef __attribute__((ext_vector_type(8))) short bf16x8;
typedef __attribute__((ext_vector_type(4))) float f32x4;

#define NPIX 4096
#define NC   128
#define RS128 0.08838834764831845f   // 1/sqrt(128)

// ---------------- prep (fused scan + copy + pack), 1024 thr ----------------
__global__ __launch_bounds__(1024) void sffa_prep(
    const float* __restrict__ x, const float* __restrict__ mask,
    ushort* __restrict__ KnW, ushort* __restrict__ QW, ushort* __restrict__ VtW,
    float* __restrict__ s0c, int* __restrict__ pixQ, int* __restrict__ cnts,
    float* __restrict__ out)
{
    __shared__ float xs[128][69];
    __shared__ float ms[64];
    __shared__ float rinv[64];
    __shared__ float ssum[64];
    __shared__ float2 part[16][64];
    __shared__ int se[64];
    __shared__ int bgn[64];
    __shared__ int tinfo[2];   // s0base, nbg
    __shared__ int wredP[16], wredT[16];
    const int tid = threadIdx.x;
    const int b = blockIdx.x >> 6, nblk = blockIdx.x & 63;
    const int n0 = nblk * 64;
    const float* xb = x + (size_t)b * NC * NPIX;
    float* ob = out + (size_t)b * NC * NPIX;

    // load x tile -> LDS (transposed view xs[c][n]) AND copy out=x (same registers)
    #pragma unroll
    for (int it = 0; it < 2; ++it) {
        int e4 = it * 1024 + tid;
        int c = e4 >> 4, n4 = (e4 & 15) * 4;
        float4 v = *(const float4*)(xb + (size_t)c * NPIX + n0 + n4);
        xs[c][n4+0] = v.x; xs[c][n4+1] = v.y; xs[c][n4+2] = v.z; xs[c][n4+3] = v.w;
        *(float4*)(ob + (size_t)c * NPIX + n0 + n4) = v;
    }
    if (tid < 16) {
        float4 mv = *(const float4*)(mask + (size_t)b * NPIX + n0 + tid * 4);
        ms[tid*4+0] = mv.x; ms[tid*4+1] = mv.y; ms[tid*4+2] = mv.z; ms[tid*4+3] = mv.w;
    }
    // full-batch mask read -> packed (bg low16 | hole high16) counts: {<n0}, {total}
    {
        const int lane = tid & 63, w = tid >> 6;
        float4 mv = *(const float4*)(mask + (size_t)b * NPIX + tid * 4);
        int f0 = mv.x < 0.5f ? 0x10000 : 1;
        int f1 = mv.y < 0.5f ? 0x10000 : 1;
        int f2 = mv.z < 0.5f ? 0x10000 : 1;
        int f3 = mv.w < 0.5f ? 0x10000 : 1;
        int p0 = tid * 4;
        int pre = 0, tot = f0 + f1 + f2 + f3;
        if (p0 + 0 < n0) pre += f0;
        if (p0 + 1 < n0) pre += f1;
        if (p0 + 2 < n0) pre += f2;
        if (p0 + 3 < n0) pre += f3;
        #pragma unroll
        for (int d = 1; d < 64; d <<= 1) {
            pre += __shfl_xor(pre, d);
            tot += __shfl_xor(tot, d);
        }
        if (lane == 0) { wredP[w] = pre; wredT[w] = tot; }
    }
    __syncthreads();
    if (tid < 64) {
        int vP = (tid < 16) ? wredP[tid] : 0;
        int vT = (tid < 16) ? wredT[tid] : 0;
        #pragma unroll
        for (int d = 1; d < 16; d <<= 1) {
            vP += __shfl_xor(vP, d);
            vT += __shfl_xor(vT, d);
        }
        int base  = __shfl(vP, 0);
        int total = __shfl(vT, 0);
        if (tid == 0 && nblk == 0) {
            cnts[b * 2]     = total & 0xffff;   // cntK
            cnts[b * 2 + 1] = total >> 16;      // cntQ
        }
        // own-tile exclusive prefix (single wave over 64 pixels)
        int f = ms[tid] > 0.5f ? 1 : 0x10000;
        int s = f;
        #pragma unroll
        for (int d = 1; d < 64; d <<= 1) {
            int t = __shfl_up(s, d);
            if (tid >= d) s += t;
        }
        se[tid] = base + s - f;
    }
    __syncthreads();
    // per-pixel norms + s0 sums
    {
        int p = tid & 63, qd = tid >> 6;    // 16 groups of 8 channels
        float m = ms[p];
        float s2 = 0.f, s1 = 0.f;
        #pragma unroll
        for (int i = 0; i < 8; ++i) {
            float xv = xs[qd*8 + i][p];
            float k = fmaf(xv, m, 1e-7f);
            s2 = fmaf(k, k, s2);
            s1 += xv;
        }
        part[qd][p] = make_float2(s2, s1);
    }
    __syncthreads();
    if (tid < 64) {
        float s2 = 0.f, s1 = 0.f;
        #pragma unroll
        for (int k = 0; k < 16; ++k) { float2 t = part[k][tid]; s2 += t.x; s1 += t.y; }
        rinv[tid] = rsqrtf(s2);
        ssum[tid] = s1 * RS128;
    }
    __syncthreads();
    // Kn & Q compacted rows, coalesced
    #pragma unroll
    for (int it = 0; it < 4; ++it) {
        int e2 = it * 1024 + tid;
        int n = e2 >> 6, cp = (e2 & 63) * 2;
        int pe = se[n];
        float x0 = xs[cp][n], x1 = xs[cp+1][n];
        if (ms[n] > 0.5f) {
            int slot = pe & 0xffff;
            float k0 = x0 + 1e-7f, k1 = x1 + 1e-7f;
            float r = rinv[n];
            __hip_bfloat162 kn;
            kn.x = __float2bfloat16(k0 * r); kn.y = __float2bfloat16(k1 * r);
            *(__hip_bfloat162*)(KnW + ((size_t)b * NPIX + slot) * NC + cp) = kn;
        } else {
            int slot = pe >> 16;
            __hip_bfloat162 q;
            q.x = __float2bfloat16(x0); q.y = __float2bfloat16(x1);
            *(__hip_bfloat162*)(QW + ((size_t)b * NPIX + slot) * NC + cp) = q;
        }
    }
    if (tid < 64) {
        if (ms[tid] < 0.5f) {
            int slot = se[tid] >> 16;
            s0c [(size_t)b * NPIX + slot] = ssum[tid];
            pixQ[(size_t)b * NPIX + slot] = n0 + tid;
        } else {
            bgn[(se[tid] & 0xffff) - (se[0] & 0xffff)] = tid;
        }
    }
    if (tid == 0) {
        tinfo[0] = se[0] & 0xffff;
        tinfo[1] = (se[63] & 0xffff) + (ms[63] > 0.5f ? 1 : 0) - (se[0] & 0xffff);
    }
    __syncthreads();
    // Vt[c][slot] direct: bg slots of this tile are contiguous [s0b, s0b+nbg)
    {
        const int s0b = tinfo[0], nbg = tinfo[1];
        const int j = tid & 63, cg = tid >> 6;     // lane j = bg index, 16 c-groups of 8
        if (j < nbg) {
            int n = bgn[j];
            ushort* vcol = VtW + (size_t)b * NC * NPIX + s0b + j;
            #pragma unroll
            for (int cc = 0; cc < 8; ++cc) {
                int c = cg * 8 + cc;
                __hip_bfloat16 h = __float2bfloat16(xs[c][n] + 1e-7f);
                vcol[(size_t)c * NPIX] = *(ushort*)&h;
            }
        }
    }
}

// ---------------- flash attention over compacted keys/queries (unchanged) ----------------
#define L_BUF 32768
#define L_P   65536
#define L_ML  75776
#define L_SZ  76800

__global__ __launch_bounds__(512, 4) void sffa_attn(
    const ushort* __restrict__ KnW, const ushort* __restrict__ QW,
    const ushort* __restrict__ VtW, const int* __restrict__ cnts,
    ushort* __restrict__ partW, float* __restrict__ mlW, int KS)
{
    __shared__ __align__(16) char smem[L_SZ];
    const int tid  = threadIdx.x;
    const int w = tid >> 6, lane = tid & 63;
    const int l15 = lane & 15, g = lane >> 4;
    const int bx = (int)blockIdx.x;
    const int per = 64 * KS;
    const int b = bx / per;
    const int rem = bx - b * per;
    const int qblk = rem / KS, ks = rem - (rem / KS) * KS;
    const int q0 = qblk * 64;
    const int cntK = cnts[b * 2], cntQ = cnts[b * 2 + 1];
    if (q0 >= cntQ) return;
    const int blk = (b * 64 + qblk) * KS + ks;

    const int nk64 = (cntK + 63) >> 6;
    const int tpk  = (nk64 + KS - 1) / KS;
    const int t0   = ks * tpk;
    const int t1   = min(t0 + tpk, nk64);
    const int NTK  = t1 - t0;

    if (NTK <= 0) {
        unsigned* pz = (unsigned*)(partW + (size_t)blk * 8192);
        #pragma unroll
        for (int i = 0; i < 8; ++i) pz[i * 512 + tid] = 0u;
        if (tid < 64)
            *(float2*)(mlW + ((size_t)blk * 64 + tid) * 2) = make_float2(-1e30f, 0.f);
        return;
    }

    const int half = w >> 2;
    const int wq   = w & 3;
    const int kbase = t0 * 64;

    const ushort* Knb = KnW + (size_t)b * NPIX * NC;
    const ushort* Qb  = QW  + (size_t)b * NPIX * NC + (size_t)q0 * NC;
    const ushort* Vtb = VtW + (size_t)b * NC * NPIX;

    // ---- stage Q tile, read q-fragments ----
    #pragma unroll
    for (int it = 0; it < 2; ++it) {
        int L = (it * 512 + tid) * 16;
        int row = L >> 8, col = L & 255;
        int4 v = *(const int4*)((const char*)Qb + L);
        *(int4*)(smem + row * 256 + (col ^ ((row & 15) << 4))) = v;
    }
    __syncthreads();
    bf16x8 qf[4];
    {
        int qrow = wq * 16 + l15;
        #pragma unroll
        for (int kc = 0; kc < 4; ++kc)
            qf[kc] = *(const bf16x8*)(smem + qrow * 256 + ((64*kc + 16*g) ^ (l15 << 4)));
    }
    __syncthreads();

    const int kOff = (tid >> 4) * 256 + (((tid & 15) * 16) ^ (((tid >> 4) & 15) << 4));
    const int cV = tid >> 3, sV = tid & 7;
    const int vOff = cV * 128 + ((sV * 16) ^ ((cV & 7) << 4));
    const int4* kgbase = (const int4*)(Knb + (size_t)kbase * NC);
    const ushort* vgbase = Vtb + (size_t)cV * NPIX + kbase + sV * 8;

    int4 pr0, pr1, pr2, pr3;
    pr0 = kgbase[tid]; pr1 = kgbase[512 + tid];
    pr2 = *(const int4*)(vgbase);
    pr3 = *(const int4*)(vgbase + (size_t)64 * NPIX);
    {
        char* base = smem;
        *(int4*)(base + kOff) = pr0;
        *(int4*)(base + kOff + 8192) = pr1;
        *(int4*)(base + 16384 + vOff) = pr2;
        *(int4*)(base + 16384 + vOff + 8192) = pr3;
    }
    if (NTK > 1) {
        pr0 = kgbase[1024 + tid]; pr1 = kgbase[1536 + tid];
        pr2 = *(const int4*)(vgbase + 64);
        pr3 = *(const int4*)(vgbase + (size_t)64 * NPIX + 64);
    }
    __syncthreads();

    f32x4 acc[8];
    const f32x4 fzero = {0.f, 0.f, 0.f, 0.f};
    #pragma unroll
    for (int i = 0; i < 8; ++i) acc[i] = fzero;
    float mrun = -1e30f, lrun = 0.f;
    char* Pw = smem + L_P + w * 1280;

    for (int kt = 0; kt < NTK; ++kt) {
        if (kt + 1 < NTK) {
            char* base = smem + ((kt + 1) & 1) * L_BUF;
            *(int4*)(base + kOff) = pr0;
            *(int4*)(base + kOff + 8192) = pr1;
            *(int4*)(base + 16384 + vOff) = pr2;
            *(int4*)(base + 16384 + vOff + 8192) = pr3;
        }
        if (kt + 2 < NTK) {
            pr0 = kgbase[(kt + 2) * 1024 + tid];
            pr1 = kgbase[(kt + 2) * 1024 + 512 + tid];
            pr2 = *(const int4*)(vgbase + (kt + 2) * 64);
            pr3 = *(const int4*)(vgbase + (size_t)64 * NPIX + (kt + 2) * 64);
        }
        char* bb = smem + (kt & 1) * L_BUF;
        f32x4 sa0 = fzero, sa1 = fzero;
        {
            const char* rb0 = bb + (half * 32 + l15) * 256;
            const char* rb1 = rb0 + 4096;
            const int sw = l15 << 4;
            __builtin_amdgcn_s_setprio(1);
            #pragma unroll
            for (int kc = 0; kc < 4; ++kc) {
                int off = (64 * kc + 16 * g) ^ sw;
                bf16x8 a0 = *(const bf16x8*)(rb0 + off);
                bf16x8 a1 = *(const bf16x8*)(rb1 + off);
                sa0 = __builtin_amdgcn_mfma_f32_16x16x32_bf16(a0, qf[kc], sa0, 0, 0, 0);
                sa1 = __builtin_amdgcn_mfma_f32_16x16x32_bf16(a1, qf[kc], sa1, 0, 0, 0);
            }
            __builtin_amdgcn_s_setprio(0);
        }
        {
            int kg0 = (t0 + kt) * 64;
            if (kg0 + 64 > cntK) {
                int kb = cntK - kg0;
                int kr = half * 32 + 4 * g;
                #pragma unroll
                for (int r = 0; r < 4; ++r) {
                    if (kr + r >= kb)      sa0[r] = -3e38f;
                    if (kr + 16 + r >= kb) sa1[r] = -3e38f;
                }
            }
        }
        float tmax = fmaxf(fmaxf(fmaxf(sa0[0], sa0[1]), fmaxf(sa0[2], sa0[3])),
                           fmaxf(fmaxf(sa1[0], sa1[1]), fmaxf(sa1[2], sa1[3])));
        tmax = fmaxf(tmax, __shfl_xor(tmax, 16));
        tmax = fmaxf(tmax, __shfl_xor(tmax, 32));
        bool grow = !__all(tmax <= mrun + 8.f);
        float mnew = grow ? fmaxf(mrun, tmax) : mrun;
        float p0[4], p1[4];
        float ts = 0.f;
        #pragma unroll
        for (int r = 0; r < 4; ++r) { p0[r] = __expf(sa0[r] - mnew); ts += p0[r]; }
        #pragma unroll
        for (int r = 0; r < 4; ++r) { p1[r] = __expf(sa1[r] - mnew); ts += p1[r]; }
        ts += __shfl_xor(ts, 16);
        ts += __shfl_xor(ts, 32);
        if (grow) {
            float sc = __expf(mrun - mnew);
            lrun = lrun * sc + ts;
            float scr[4];
            #pragma unroll
            for (int r = 0; r < 4; ++r) scr[r] = __shfl(sc, 4 * g + r);
            #pragma unroll
            for (int ct = 0; ct < 8; ++ct) {
                acc[ct][0] *= scr[0]; acc[ct][1] *= scr[1];
                acc[ct][2] *= scr[2]; acc[ct][3] *= scr[3];
            }
            mrun = mnew;
        } else {
            lrun += ts;
        }
        union { __hip_bfloat162 h; unsigned u; } ua0, ua1, ub0, ub1;
        ua0.h.x = __float2bfloat16(p0[0]); ua0.h.y = __float2bfloat16(p0[1]);
        ua1.h.x = __float2bfloat16(p0[2]); ua1.h.y = __float2bfloat16(p0[3]);
        ub0.h.x = __float2bfloat16(p1[0]); ub0.h.y = __float2bfloat16(p1[1]);
        ub1.h.x = __float2bfloat16(p1[2]); ub1.h.y = __float2bfloat16(p1[3]);
        *(int2*)(Pw + l15 * 80 +      8 * g) = make_int2((int)ua0.u, (int)ua1.u);
        *(int2*)(Pw + l15 * 80 + 32 + 8 * g) = make_int2((int)ub0.u, (int)ub1.u);
        bf16x8 pf = *(const bf16x8*)(Pw + l15 * 80 + 16 * g);
        {
            const char* vb = bb + 16384;
            __builtin_amdgcn_s_setprio(1);
            #pragma unroll
            for (int ct = 0; ct < 8; ++ct) {
                int c = 16 * ct + l15;
                bf16x8 vf = *(const bf16x8*)(vb + c * 128 +
                                             ((64 * half + 16 * g) ^ ((c & 7) << 4)));
                acc[ct] = __builtin_amdgcn_mfma_f32_16x16x32_bf16(pf, vf, acc[ct], 0, 0, 0);
            }
            __builtin_amdgcn_s_setprio(0);
        }
        __syncthreads();
    }

    float* ma = (float*)(smem + L_ML);
    float* la = ma + 64; float* mb = la + 64; float* lb = mb + 64;
    const int q = wq * 16 + l15;
    if (g == 0) {
        if (half == 0) { ma[q] = mrun; la[q] = lrun; }
        else           { mb[q] = mrun; lb[q] = lrun; }
    }
    __syncthreads();
    float* agg = (float*)smem;
    {
        float mstar = fmaxf(ma[q], mb[q]);
        float f = __expf(mrun - mstar);
        float fr[4];
        #pragma unroll
        for (int r = 0; r < 4; ++r) fr[r] = __shfl(f, 4 * g + r);
        if (half == 1) {
            #pragma unroll
            for (int ct = 0; ct < 8; ++ct) {
                int c = 16 * ct + l15;
                #pragma unroll
                for (int r = 0; r < 4; ++r)
                    agg[c * 68 + wq * 16 + 4 * g + r] = acc[ct][r] * fr[r];
            }
        }
        __syncthreads();
        if (half == 0) {
            #pragma unroll
            for (int ct = 0; ct < 8; ++ct) {
                int c = 16 * ct + l15;
                #pragma unroll
                for (int r = 0; r < 4; ++r) {
                    int idx = c * 68 + wq * 16 + 4 * g + r;
                    agg[idx] = acc[ct][r] * fr[r] + agg[idx];
                }
            }
        }
    }
    __syncthreads();
    if (tid < 64) {
        float M = fmaxf(ma[tid], mb[tid]);
        float ls = la[tid] * __expf(ma[tid] - M) + lb[tid] * __expf(mb[tid] - M);
        *(float2*)(mlW + ((size_t)blk * 64 + tid) * 2) = make_float2(M, ls);
    }
    ushort* pdst = partW + (size_t)blk * 8192;
    #pragma unroll
    for (int it = 0; it < 8; ++it) {
        int idx = it * 512 + tid;
        int c = idx >> 5, n2 = (idx & 31) * 2;
        __hip_bfloat162 h;
        h.x = __float2bfloat16(agg[c * 68 + n2]);
        h.y = __float2bfloat16(agg[c * 68 + n2 + 1]);
        *(__hip_bfloat162*)(pdst + c * 64 + n2) = h;
    }
}

// ---------------- comb: slot-space vectorized combine + scatter (4-way c-split) ----------------
__global__ __launch_bounds__(256) void sffa_comb(
    const ushort* __restrict__ partW, const float* __restrict__ mlW,
    const float* __restrict__ s0c, const int* __restrict__ pixQ,
    const int* __restrict__ cnts, float* __restrict__ out, int KS)
{
    __shared__ float wgtL[4][64];
    __shared__ int pixnL[64];
    const int tid = threadIdx.x;
    const int bx = blockIdx.x;
    const int b = bx >> 8, qb = (bx >> 2) & 63, ch = bx & 3;
    const int cntK = cnts[b * 2], cntQ = cnts[b * 2 + 1];
    if (qb * 64 >= cntQ) return;
    const int blkbase = (b * 64 + qb) * KS;
    const float m0f = (float)(NPIX - cntK);

    if (tid < 64) {
        int slot = qb * 64 + tid;
        int pix = -1;
        if (slot < cntQ) {
            pix = pixQ[(size_t)b * NPIX + slot];
            float s0 = s0c[(size_t)b * NPIX + slot];
            float M = s0;
            float2 mls[4];
            #pragma unroll
            for (int k = 0; k < 4; ++k) {
                if (k < KS) {
                    mls[k] = *(const float2*)(mlW + ((size_t)(blkbase + k) * 64 + tid) * 2);
                    M = fmaxf(M, mls[k].x);
                }
            }
            float L = m0f * __expf(s0 - M);
            #pragma unroll
            for (int k = 0; k < 4; ++k)
                if (k < KS) L += mls[k].y * __expf(mls[k].x - M);
            float Li = 1.f / L;
            #pragma unroll
            for (int k = 0; k < 4; ++k)
                if (k < KS) wgtL[k][tid] = __expf(mls[k].x - M) * Li;
        }
        pixnL[tid] = pix;
    }
    __syncthreads();

    float* ob = out + (size_t)b * NC * NPIX;
    const ushort* pb = partW + (size_t)blkbase * 8192;
    {
        int cl = tid >> 3, grp = tid & 7;       // 32 c per chunk, 8-slot groups
        int c = ch * 32 + cl;
        float v[8] = {0.f,0.f,0.f,0.f,0.f,0.f,0.f,0.f};
        #pragma unroll
        for (int k = 0; k < 4; ++k) {
            if (k < KS) {
                ushort u[8];
                *(int4*)u = *(const int4*)(pb + (size_t)k * 8192 + c * 64 + grp * 8);
                #pragma unroll
                for (int j = 0; j < 8; ++j)
                    v[j] = fmaf(__uint_as_float((unsigned)u[j] << 16),
                                wgtL[k][grp * 8 + j], v[j]);
            }
        }
        #pragma unroll
        for (int j = 0; j < 8; ++j) {
            int pix = pixnL[grp * 8 + j];
            if (pix >= 0) ob[(size_t)c * NPIX + pix] = v[j];
        }
    }
}

extern "C" void kernel_launch(void* const* d_in, const int* in_sizes, int n_in,
                              void* d_out, int out_size, void* d_ws, size_t ws_size,
                              hipStream_t stream) {
    const float* x    = (const float*)d_in[0];
    const float* mask = (const float*)d_in[1];
    char* ws = (char*)d_ws;
    const size_t MBy = 1024 * 1024;
    const size_t KBy = 1024;

    ushort* KnW = (ushort*)(ws);                      // 4 MB compact Kn
    ushort* QW  = (ushort*)(ws + 4 * MBy);            // 4 MB compact Q
    ushort* VtW = (ushort*)(ws + 8 * MBy);            // 4 MB compact V^T

    size_t need4 = 12 * MBy + 4 * 4 * MBy + 1 * MBy;
    int KS = (ws_size >= need4) ? 4 : 2;
    ushort* partW = (ushort*)(ws + 12 * MBy);                       // KS*4 MB
    char* tail = ws + 12 * MBy + (size_t)KS * 4 * MBy;
    float* mlW    = (float*)(tail);                                  // 512 KB
    float* s0c    = (float*)(tail + 576 * KBy);                      // 64 KB
    int*   pixQ   = (int*)(tail + 640 * KBy);                        // 64 KB
    int*   cnts   = (int*)(tail + 704 * KBy);                        // 32 B

    sffa_prep <<<256, 1024, 0, stream>>>(x, mask, KnW, QW, VtW, s0c, pixQ, cnts,
                                         (float*)d_out);
    sffa_attn <<<4 * 64 * KS, 512, 0, stream>>>(KnW, QW, VtW, cnts, partW, mlW, KS);
    sffa_comb <<<4 * 64 * 4, 256, 0, stream>>>(partW, mlW, s0c, pixQ, cnts,
                                               (float*)d_out, KS);
}